// Round 6
// baseline (264.786 us; speedup 1.0000x reference)
//
#include <hip/hip_runtime.h>
#include <hip/hip_fp16.h>
#include <math.h>

#define N 20000
#define F 128
#define C1 256   // HEADS*HIDDEN
#define HEADS 8
#define HID 32
#define NC 40
#define NCP 64   // padded h2h row stride (1 cache line)
#define NEG 0.2f

#define BSHIFT 7
#define NB 157        // buckets of 128 nodes
#define HBLOCKS 256
#define HM (NB * HBLOCKS)

#define PREPW_BLOCKS 16
#define W2PW_BLOCKS 6   // 24 frags * 64 lanes = 1536 half8 slots

#define QS ((size_t)N * 64)   // quarter-plane element stride

typedef _Float16 half8 __attribute__((ext_vector_type(8)));
typedef float f32x4 __attribute__((ext_vector_type(4)));

__device__ __forceinline__ int edge_stride(const int* ei) {
    return (ei[1] == 0 && ei[3] == 0 && ei[5] == 0 && ei[7] == 0 && ei[9] == 0) ? 2 : 1;
}

__device__ __forceinline__ float lrelu(float v) { return v > 0.f ? v : NEG * v; }

// ---- K0: fused prep (W1 swizzle + W2 swizzle) + bucket histogram (LDS atomics only)
__global__ __launch_bounds__(256) void k_misc(
    const float* __restrict__ W1, _Float16* __restrict__ w1sw,
    const float* __restrict__ W2, _Float16* __restrict__ w2sw,
    const int* __restrict__ ei, int E, int* __restrict__ hist)
{
    const int b = blockIdx.x;
    const int tid = threadIdx.x;
    if (b < PREPW_BLOCKS) {
        const int slot = b * 256 + tid;
        const int lane = slot & 63;
        const int tile = slot >> 6;
        const int nt = tile & 15, ks = tile >> 4;
        const int n = nt * 16 + (lane & 15);
        const int k0 = ks * 32 + (lane >> 4) * 8;
        half8 tmp;
#pragma unroll
        for (int j = 0; j < 8; j++) tmp[j] = (_Float16)W1[(k0 + j) * C1 + n];
        *reinterpret_cast<half8*>(&w1sw[(size_t)slot * 8]) = tmp;
    } else if (b < PREPW_BLOCKS + W2PW_BLOCKS) {
        const int slot = (b - PREPW_BLOCKS) * 256 + tid;   // 0..1535
        const int lane = slot & 63;
        const int f = slot >> 6;          // 0..23
        const int nt = f % 3, ks = f / 3;
        const int n = nt * 16 + (lane & 15);
        const int k0 = ks * 32 + (lane >> 4) * 8;
        half8 tmp;
#pragma unroll
        for (int j = 0; j < 8; j++)
            tmp[j] = (n < NC) ? (_Float16)W2[(k0 + j) * NC + n] : (_Float16)0.f;
        *reinterpret_cast<half8*>(&w2sw[(size_t)slot * 8]) = tmp;
    } else {
        __shared__ int hcnt[NB];
        const int hb = b - PREPW_BLOCKS - W2PW_BLOCKS;
        if (tid < NB) hcnt[tid] = 0;
        __syncthreads();
        const int ET = E + N;
        const int per = (ET + HBLOCKS - 1) / HBLOCKS;
        const int lo = hb * per;
        const int hi = (lo + per < ET) ? (lo + per) : ET;
        const int st = edge_stride(ei);
        for (int i = lo + tid; i < hi; i += 256) {
            const int d = (i < E) ? ei[(size_t)st * (E + i)] : (i - E);
            atomicAdd(&hcnt[d >> BSHIFT], 1);
        }
        __syncthreads();
        if (tid < NB) hist[tid * HBLOCKS + hb] = hcnt[tid];
    }
}

// ---- K1: h1 = x @ W1 via MFMA; h1 written as FOUR 64-ch quarter planes
//      (each 2.56 MB -> L2-resident per XCD with blockIdx&3 steering in k_agg1).
__global__ __launch_bounds__(256) void k_gemm1_mfma(
    const float* __restrict__ x, const _Float16* __restrict__ w1sw,
    const float* __restrict__ a1s, const float* __restrict__ a1d,
    __half* __restrict__ qh1,
    float* __restrict__ as1, float* __restrict__ ad1)
{
    const int lane = threadIdx.x & 63;
    const int wid = (blockIdx.x * 256 + threadIdx.x) >> 6;
    const int m0 = wid * 16;
    const int g = lane >> 4, lm = lane & 15;
    const int arow = m0 + lm;
    half8 a[4];
    if (arow < N) {
        const float* xr = x + (size_t)arow * F;
#pragma unroll
        for (int ks = 0; ks < 4; ks++) {
            const float4 v0 = *reinterpret_cast<const float4*>(&xr[ks * 32 + g * 8]);
            const float4 v1 = *reinterpret_cast<const float4*>(&xr[ks * 32 + g * 8 + 4]);
            half8 t;
            t[0] = (_Float16)v0.x; t[1] = (_Float16)v0.y; t[2] = (_Float16)v0.z; t[3] = (_Float16)v0.w;
            t[4] = (_Float16)v1.x; t[5] = (_Float16)v1.y; t[6] = (_Float16)v1.z; t[7] = (_Float16)v1.w;
            a[ks] = t;
        }
    } else {
#pragma unroll
        for (int ks = 0; ks < 4; ks++) {
            half8 t;
#pragma unroll
            for (int j = 0; j < 8; j++) t[j] = (_Float16)0.f;
            a[ks] = t;
        }
    }
    const int rbase = m0 + g * 4;
    float ps[4] = {0.f, 0.f, 0.f, 0.f}, pd[4] = {0.f, 0.f, 0.f, 0.f};
#pragma unroll
    for (int nt = 0; nt < 16; nt++) {
        f32x4 acc = {0.f, 0.f, 0.f, 0.f};
#pragma unroll
        for (int ks = 0; ks < 4; ks++) {
            const half8 bfr = *reinterpret_cast<const half8*>(&w1sw[(size_t)((ks * 16 + nt) * 64 + lane) * 8]);
            acc = __builtin_amdgcn_mfma_f32_16x16x32_f16(a[ks], bfr, acc, 0, 0, 0);
        }
        const int col = nt * 16 + lm;
        const int q = col >> 6, cq = col & 63;
        const float av = a1s[col], dv = a1d[col];
#pragma unroll
        for (int r = 0; r < 4; r++) {
            const int row = rbase + r;
            if (row < N) qh1[(size_t)q * QS + (size_t)row * 64 + cq] = __float2half((float)acc[r]);
            ps[r] = fmaf((float)acc[r], av, ps[r]);
            pd[r] = fmaf((float)acc[r], dv, pd[r]);
        }
        if (nt & 1) {
#pragma unroll
            for (int off = 1; off <= 8; off <<= 1) {
#pragma unroll
                for (int r = 0; r < 4; r++) {
                    ps[r] += __shfl_xor(ps[r], off);
                    pd[r] += __shfl_xor(pd[r], off);
                }
            }
            if (lm == 0) {
                const int head = nt >> 1;
#pragma unroll
                for (int r = 0; r < 4; r++) {
                    const int row = rbase + r;
                    if (row < N) {
                        as1[row * HEADS + head] = ps[r];
                        ad1[row * HEADS + head] = pd[r];
                    }
                }
            }
#pragma unroll
            for (int r = 0; r < 4; r++) { ps[r] = 0.f; pd[r] = 0.f; }
        }
    }
}

// ---- K3: scatter with FUSED scan. Each block redundantly computes the full
//      2D exclusive scan of hist (L2-resident, ~160KB read) -> its own cursor
//      column; block 0 also writes bucket starts for k_bucket.
__global__ __launch_bounds__(256) void k_scatter2(
    const int* __restrict__ ei, int E, const int* __restrict__ hist,
    int* __restrict__ buck, int* __restrict__ bstart)
{
    __shared__ int cur[NB];
    __shared__ int bs[160];
    __shared__ int wbase[4];
    const int hb = blockIdx.x;
    const int tid = threadIdx.x;
    const int lane = tid & 63, wid = tid >> 6;
    int rp = 0;
    if (tid < NB) {
        const int4* hp = (const int4*)&hist[tid * HBLOCKS];
        int s = 0;
#pragma unroll 4
        for (int k = 0; k < 64; k++) {
            const int4 v = hp[k];
            s += (v.x + v.y) + (v.z + v.w);
            const int b4 = 4 * k;
            rp += ((b4 + 0) < hb ? v.x : 0) + ((b4 + 1) < hb ? v.y : 0)
                + ((b4 + 2) < hb ? v.z : 0) + ((b4 + 3) < hb ? v.w : 0);
        }
        bs[tid] = s;
    }
    __syncthreads();
    // exclusive scan of bs[0..NB)
    const int vin = (tid < NB) ? bs[tid] : 0;
    int v = vin;
#pragma unroll
    for (int off = 1; off < 64; off <<= 1) {
        const int u = __shfl_up(v, off, 64);
        if (lane >= off) v += u;
    }
    if (lane == 63) wbase[wid] = v;
    __syncthreads();
    if (tid < 64) {
        int w = (lane < 4) ? wbase[lane] : 0;
        const int orig = w;
#pragma unroll
        for (int off = 1; off < 4; off <<= 1) {
            const int u = __shfl_up(w, off, 64);
            if (lane >= off) w += u;
        }
        if (lane < 4) wbase[lane] = w - orig;
    }
    __syncthreads();
    if (tid < NB) {
        const int base = wbase[wid] + v - vin;   // exclusive global base of bucket tid
        cur[tid] = base + rp;
        if (hb == 0) bstart[tid] = base;
    }
    __syncthreads();
    const int ET = E + N;
    const int per = (ET + HBLOCKS - 1) / HBLOCKS;
    const int lo = hb * per;
    const int hi = (lo + per < ET) ? (lo + per) : ET;
    const int st = edge_stride(ei);
    for (int i = lo + tid; i < hi; i += 256) {
        int s, d;
        if (i < E) { s = ei[(size_t)st * i]; d = ei[(size_t)st * (E + i)]; }
        else       { s = i - E; d = i - E; }
        const int slot = atomicAdd(&cur[d >> BSHIFT], 1);
        buck[slot] = ((d & 127) << 16) | s;
    }
}

// ---- K4: per-bucket counting sort -> csr + rowptr (+ zero sentinels past ET).
__global__ __launch_bounds__(256) void k_bucket(
    const int* __restrict__ bstart, const int* __restrict__ buck, int ET,
    int* __restrict__ csr, int* __restrict__ rowptr)
{
    __shared__ int cnt[128];
    __shared__ int pfx[128];
    const int b = blockIdx.x;
    const int tid = threadIdx.x;
    const int start = bstart[b];
    const int end = (b == NB - 1) ? ET : bstart[b + 1];
    if (tid < 128) cnt[tid] = 0;
    __syncthreads();
    for (int i = start + tid; i < end; i += 256)
        atomicAdd(&cnt[buck[i] >> 16], 1);
    __syncthreads();
    if (tid < 128) pfx[tid] = cnt[tid];
    __syncthreads();
    for (int off = 1; off < 128; off <<= 1) {
        int u = 0;
        if (tid < 128 && tid >= off) u = pfx[tid - off];
        __syncthreads();
        if (tid < 128) pfx[tid] += u;
        __syncthreads();
    }
    if (tid < 128) {
        const int node = b * 128 + tid;
        const int ebase = start + pfx[tid] - cnt[tid];
        if (node < N) rowptr[node] = ebase;
        cnt[tid] = ebase;
    }
    if (b == NB - 1 && tid == 0) rowptr[N] = ET;
    if (b == NB - 1 && tid < 32) csr[ET + tid] = 0;   // sentinels: safe paired reads
    __syncthreads();
    for (int i = start + tid; i < end; i += 256) {
        const int val = buck[i];
        const int slot = atomicAdd(&cnt[val >> 16], 1);
        csr[slot] = val & 0xFFFF;
    }
}

// ---- K6: layer-1 aggregation, one WAVE per (node, quarter=64ch), R1-style body.
//      Lane: 2 channels (half2 gather, 128B/line) x 2 edges/iter (lane-32 parity);
//      weight computed redundantly per 16-lane group (no cross-lane on critical
//      path). Quarter plane is 2.56MB -> L2-resident (hq = blockIdx&3 steering).
//      One shfl_xor(32) pair at the end merges the two edge-parity halves.
__global__ __launch_bounds__(256) void k_agg1(
    const int* __restrict__ rowptr, const int* __restrict__ csr,
    const __half* __restrict__ qh1,
    const float* __restrict__ as1, const float* __restrict__ ad1,
    const float* __restrict__ b1, __half* __restrict__ h1p)
{
    const int tid = threadIdx.x;
    const int lane = tid & 63;
    const int wv = tid >> 6;
    const int hq = blockIdx.x & 3;               // quarter -> XCD steering
    const int n = (blockIdx.x >> 2) * 4 + wv;    // node
    const int l5 = lane & 31;
    const int es = lane >> 5;                    // edge parity for this lane
    const int cq = l5 * 2;                       // channel pair within quarter
    const int head = hq * 2 + (l5 >> 4);
    const float dv = ad1[n * HEADS + head];
    const int beg = rowptr[n], end = rowptr[n + 1];
    const __half* plane = qh1 + (size_t)hq * QS;
    float ax = 0.f, ay = 0.f, accw = 0.f;
#pragma unroll 4
    for (int cs = beg; cs < end; cs += 2) {
        const int s0 = csr[cs];
        const int s1 = csr[cs + 1];              // sentinel-safe
        const int s = es ? s1 : s0;
        const float av = as1[s * HEADS + head];  // 16-lane broadcast
        const float w = (cs + es < end) ? __expf(lrelu(av + dv)) : 0.f;
        const float2 g = __half22float2(*reinterpret_cast<const __half2*>(&plane[(size_t)s * 64 + cq]));
        accw += w;
        ax = fmaf(w, g.x, ax);
        ay = fmaf(w, g.y, ay);
    }
    accw += __shfl_xor(accw, 32);
    ax += __shfl_xor(ax, 32);
    ay += __shfl_xor(ay, 32);
    if (lane < 32) {
        const float inv = 1.f / accw;
        const int ch = hq * 64 + cq;
        float ox = ax * inv + b1[ch];
        float oy = ay * inv + b1[ch + 1];
        ox = (ox > 0.f) ? ox : (__expf(ox) - 1.f);
        oy = (oy > 0.f) ? oy : (__expf(oy) - 1.f);
        *reinterpret_cast<__half2*>(&h1p[(size_t)n * C1 + ch]) = __floats2half2_rn(ox, oy);
    }
}

// ---- K7: h2 = h1p @ W2 via MFMA (NC=40 padded to 3x16 col tiles); fused as2/ad2.
//      h2h stored with row stride NCP=64 halves (128B = exactly one cache line).
__global__ __launch_bounds__(256) void k_gemm2_mfma(
    const __half* __restrict__ h1p, const _Float16* __restrict__ w2sw,
    const float* __restrict__ a2s, const float* __restrict__ a2d,
    __half* __restrict__ h2h, float* __restrict__ as2, float* __restrict__ ad2)
{
    const int lane = threadIdx.x & 63;
    const int wid = (blockIdx.x * 256 + threadIdx.x) >> 6;
    const int m0 = wid * 16;
    const int g = lane >> 4, lm = lane & 15;
    const int arow = m0 + lm;
    half8 a[8];
    if (arow < N) {
        const __half* hr = h1p + (size_t)arow * C1;
#pragma unroll
        for (int ks = 0; ks < 8; ks++)
            a[ks] = *reinterpret_cast<const half8*>(&hr[ks * 32 + g * 8]);
    } else {
#pragma unroll
        for (int ks = 0; ks < 8; ks++) {
            half8 t;
#pragma unroll
            for (int j = 0; j < 8; j++) t[j] = (_Float16)0.f;
            a[ks] = t;
        }
    }
    f32x4 acc[3];
#pragma unroll
    for (int nt = 0; nt < 3; nt++) acc[nt] = (f32x4){0.f, 0.f, 0.f, 0.f};
#pragma unroll
    for (int ks = 0; ks < 8; ks++) {
#pragma unroll
        for (int nt = 0; nt < 3; nt++) {
            const half8 bfr = *reinterpret_cast<const half8*>(&w2sw[(size_t)((ks * 3 + nt) * 64 + lane) * 8]);
            acc[nt] = __builtin_amdgcn_mfma_f32_16x16x32_f16(a[ks], bfr, acc[nt], 0, 0, 0);
        }
    }
    const int rbase = m0 + g * 4;
    float av[3], dvv[3];
#pragma unroll
    for (int nt = 0; nt < 3; nt++) {
        const int col = nt * 16 + lm;
        av[nt]  = (col < NC) ? a2s[col] : 0.f;
        dvv[nt] = (col < NC) ? a2d[col] : 0.f;
    }
#pragma unroll
    for (int r = 0; r < 4; r++) {
        const int row = rbase + r;
        float ps = 0.f, pd = 0.f;
#pragma unroll
        for (int nt = 0; nt < 3; nt++) {
            const float v = (float)acc[nt][r];
            const int col = nt * 16 + lm;
            if (row < N && col < NC) h2h[(size_t)row * NCP + col] = __float2half(v);
            ps = fmaf(v, av[nt], ps);
            pd = fmaf(v, dvv[nt], pd);
        }
#pragma unroll
        for (int off = 1; off <= 8; off <<= 1) {
            ps += __shfl_xor(ps, off);
            pd += __shfl_xor(pd, off);
        }
        if (lm == 0 && row < N) { as2[row] = ps; ad2[row] = pd; }
    }
}

// ---- K8: layer-2 aggregation + bias + log_softmax. One wave/node, unroll 8.
//      h2h padded to one line/row and fully L2-resident (2.56 MB).
__global__ __launch_bounds__(256) void k_agg2(
    const int* __restrict__ rowptr, const int* __restrict__ csr,
    const __half* __restrict__ h2h, const float* __restrict__ as2,
    const float* __restrict__ ad2, const float* __restrict__ b2,
    float* __restrict__ out)
{
    const int lane = threadIdx.x & 63;
    const int n = (blockIdx.x * blockDim.x + threadIdx.x) >> 6;
    const int c = lane;
    const int cc = (c < NC) ? c : (NC - 1);
    const float adv = ad2[n];
    const int beg = rowptr[n], end = rowptr[n + 1];
    float acc = 0.f, accw = 0.f;
    int e = beg;
    for (; e + 7 < end; e += 8) {
        int s[8];
        float w[8], g[8];
#pragma unroll
        for (int j = 0; j < 8; j++) s[j] = csr[e + j];
#pragma unroll
        for (int j = 0; j < 8; j++) w[j] = __expf(lrelu(as2[s[j]] + adv));
#pragma unroll
        for (int j = 0; j < 8; j++) g[j] = __half2float(h2h[(size_t)s[j] * NCP + cc]);
#pragma unroll
        for (int j = 0; j < 8; j++) {
            accw += w[j];
            acc = fmaf(w[j], g[j], acc);
        }
    }
    for (; e + 3 < end; e += 4) {
        const int s0 = csr[e], s1 = csr[e + 1], s2 = csr[e + 2], s3 = csr[e + 3];
        const float w0 = __expf(lrelu(as2[s0] + adv));
        const float w1 = __expf(lrelu(as2[s1] + adv));
        const float w2 = __expf(lrelu(as2[s2] + adv));
        const float w3 = __expf(lrelu(as2[s3] + adv));
        const float g0 = __half2float(h2h[(size_t)s0 * NCP + cc]);
        const float g1 = __half2float(h2h[(size_t)s1 * NCP + cc]);
        const float g2 = __half2float(h2h[(size_t)s2 * NCP + cc]);
        const float g3 = __half2float(h2h[(size_t)s3 * NCP + cc]);
        accw += (w0 + w1) + (w2 + w3);
        acc = fmaf(w0, g0, acc);
        acc = fmaf(w1, g1, acc);
        acc = fmaf(w2, g2, acc);
        acc = fmaf(w3, g3, acc);
    }
    for (; e < end; e++) {
        const int s = csr[e];
        const float w = __expf(lrelu(as2[s] + adv));
        accw += w;
        acc = fmaf(w, __half2float(h2h[(size_t)s * NCP + cc]), acc);
    }
    const float v = acc / accw + b2[cc];
    float m = (c < NC) ? v : -1e30f;
#pragma unroll
    for (int off = 32; off >= 1; off >>= 1) m = fmaxf(m, __shfl_xor(m, off));
    float S = (c < NC) ? __expf(v - m) : 0.f;
#pragma unroll
    for (int off = 32; off >= 1; off >>= 1) S += __shfl_xor(S, off);
    if (c < NC) out[(size_t)n * NC + c] = v - m - logf(S);
}

extern "C" void kernel_launch(void* const* d_in, const int* in_sizes, int n_in,
                              void* d_out, int out_size, void* d_ws, size_t ws_size,
                              hipStream_t stream)
{
    const float* x   = (const float*)d_in[0];
    const int*   ei  = (const int*)d_in[1];
    const float* W1  = (const float*)d_in[2];
    const float* a1s = (const float*)d_in[3];
    const float* a1d = (const float*)d_in[4];
    const float* b1  = (const float*)d_in[5];
    const float* W2  = (const float*)d_in[6];
    const float* a2s = (const float*)d_in[7];
    const float* a2d = (const float*)d_in[8];
    const float* b2  = (const float*)d_in[9];
    float* out = (float*)d_out;

    const int E  = in_sizes[1] / 2;
    const int ET = E + N;

    auto align64 = [](size_t v) { return (v + 63) & ~(size_t)63; };
    char* ws = (char*)d_ws;
    size_t off = 0;
    _Float16* w1sw = (_Float16*)(ws + off); off = align64(off + (size_t)4096 * 8 * 2);
    _Float16* w2sw = (_Float16*)(ws + off); off = align64(off + (size_t)1536 * 8 * 2);
    __half* qh1 = (__half*)(ws + off); off = align64(off + (size_t)N * C1 * 2);   // 4 quarter planes
    __half* h1p = (__half*)(ws + off); off = align64(off + (size_t)N * C1 * 2);
    __half* h2h = (__half*)(ws + off); off = align64(off + (size_t)N * NCP * 2);
    float* as1 = (float*)(ws + off); off = align64(off + (size_t)N * HEADS * 4);
    float* ad1 = (float*)(ws + off); off = align64(off + (size_t)N * HEADS * 4);
    float* as2 = (float*)(ws + off); off = align64(off + (size_t)N * 4);
    float* ad2 = (float*)(ws + off); off = align64(off + (size_t)N * 4);
    int* hist   = (int*)(ws + off); off = align64(off + (size_t)HM * 4);
    int* bstart = (int*)(ws + off); off = align64(off + (size_t)NB * 4);
    int* buck   = (int*)(ws + off); off = align64(off + (size_t)ET * 4);
    int* rowptr = (int*)(ws + off); off = align64(off + (size_t)(N + 1) * 4);
    int* csr    = (int*)(ws + off); off = align64(off + (size_t)ET * 4 + 128);

    k_misc<<<PREPW_BLOCKS + W2PW_BLOCKS + HBLOCKS, 256, 0, stream>>>(W1, w1sw, W2, w2sw, ei, E, hist);
    k_gemm1_mfma<<<313, 256, 0, stream>>>(x, w1sw, a1s, a1d, qh1, as1, ad1);
    k_scatter2<<<HBLOCKS, 256, 0, stream>>>(ei, E, hist, buck, bstart);
    k_bucket<<<NB, 256, 0, stream>>>(bstart, buck, ET, csr, rowptr);
    k_agg1<<<N, 256, 0, stream>>>(rowptr, csr, qh1, as1, ad1, b1, h1p);
    k_gemm2_mfma<<<313, 256, 0, stream>>>(h1p, w2sw, a2s, a2d, h2h, as2, ad2);
    k_agg2<<<5000, 256, 0, stream>>>(rowptr, csr, h2h, as2, ad2, b2, out);
}

// Round 7
// 204.305 us; speedup vs baseline: 1.2960x; 1.2960x over previous
//
#include <hip/hip_runtime.h>
#include <hip/hip_fp16.h>
#include <math.h>

#define N 20000
#define F 128
#define C1 256   // HEADS*HIDDEN
#define HEADS 8
#define HID 32
#define NC 40
#define NCP 64   // padded h2h row stride (1 cache line)
#define NEG 0.2f

#define BSHIFT 7
#define NB 157        // buckets of 128 nodes
#define HBLOCKS 256
#define HM (NB * HBLOCKS)

#define PREPW_BLOCKS 16
#define W2PW_BLOCKS 6   // 24 frags * 64 lanes = 1536 half8 slots

#define QS ((size_t)N * 64)   // quarter-plane element stride

typedef _Float16 half8 __attribute__((ext_vector_type(8)));
typedef float f32x4 __attribute__((ext_vector_type(4)));

__device__ __forceinline__ int edge_stride(const int* ei) {
    return (ei[1] == 0 && ei[3] == 0 && ei[5] == 0 && ei[7] == 0 && ei[9] == 0) ? 2 : 1;
}

__device__ __forceinline__ float lrelu(float v) { return v > 0.f ? v : NEG * v; }

// ---- K0: fused prep (W1 swizzle + W2 swizzle) + bucket histogram (LDS atomics only)
__global__ __launch_bounds__(256) void k_misc(
    const float* __restrict__ W1, _Float16* __restrict__ w1sw,
    const float* __restrict__ W2, _Float16* __restrict__ w2sw,
    const int* __restrict__ ei, int E, int* __restrict__ hist)
{
    const int b = blockIdx.x;
    const int tid = threadIdx.x;
    if (b < PREPW_BLOCKS) {
        const int slot = b * 256 + tid;
        const int lane = slot & 63;
        const int tile = slot >> 6;
        const int nt = tile & 15, ks = tile >> 4;
        const int n = nt * 16 + (lane & 15);
        const int k0 = ks * 32 + (lane >> 4) * 8;
        half8 tmp;
#pragma unroll
        for (int j = 0; j < 8; j++) tmp[j] = (_Float16)W1[(k0 + j) * C1 + n];
        *reinterpret_cast<half8*>(&w1sw[(size_t)slot * 8]) = tmp;
    } else if (b < PREPW_BLOCKS + W2PW_BLOCKS) {
        const int slot = (b - PREPW_BLOCKS) * 256 + tid;   // 0..1535
        const int lane = slot & 63;
        const int f = slot >> 6;          // 0..23
        const int nt = f % 3, ks = f / 3;
        const int n = nt * 16 + (lane & 15);
        const int k0 = ks * 32 + (lane >> 4) * 8;
        half8 tmp;
#pragma unroll
        for (int j = 0; j < 8; j++)
            tmp[j] = (n < NC) ? (_Float16)W2[(k0 + j) * NC + n] : (_Float16)0.f;
        *reinterpret_cast<half8*>(&w2sw[(size_t)slot * 8]) = tmp;
    } else {
        __shared__ int hcnt[NB];
        const int hb = b - PREPW_BLOCKS - W2PW_BLOCKS;
        if (tid < NB) hcnt[tid] = 0;
        __syncthreads();
        const int ET = E + N;
        const int per = (ET + HBLOCKS - 1) / HBLOCKS;
        const int lo = hb * per;
        const int hi = (lo + per < ET) ? (lo + per) : ET;
        const int st = edge_stride(ei);
        for (int i = lo + tid; i < hi; i += 256) {
            const int d = (i < E) ? ei[(size_t)st * (E + i)] : (i - E);
            atomicAdd(&hcnt[d >> BSHIFT], 1);
        }
        __syncthreads();
        if (tid < NB) hist[tid * HBLOCKS + hb] = hcnt[tid];
    }
}

// ---- K1: h1 = x @ W1 via MFMA; h1 written as FOUR 64-ch quarter planes
//      (each 2.56 MB -> L2-resident per XCD with blockIdx&3 steering in k_agg1).
__global__ __launch_bounds__(256) void k_gemm1_mfma(
    const float* __restrict__ x, const _Float16* __restrict__ w1sw,
    const float* __restrict__ a1s, const float* __restrict__ a1d,
    __half* __restrict__ qh1,
    float* __restrict__ as1, float* __restrict__ ad1)
{
    const int lane = threadIdx.x & 63;
    const int wid = (blockIdx.x * 256 + threadIdx.x) >> 6;
    const int m0 = wid * 16;
    const int g = lane >> 4, lm = lane & 15;
    const int arow = m0 + lm;
    half8 a[4];
    if (arow < N) {
        const float* xr = x + (size_t)arow * F;
#pragma unroll
        for (int ks = 0; ks < 4; ks++) {
            const float4 v0 = *reinterpret_cast<const float4*>(&xr[ks * 32 + g * 8]);
            const float4 v1 = *reinterpret_cast<const float4*>(&xr[ks * 32 + g * 8 + 4]);
            half8 t;
            t[0] = (_Float16)v0.x; t[1] = (_Float16)v0.y; t[2] = (_Float16)v0.z; t[3] = (_Float16)v0.w;
            t[4] = (_Float16)v1.x; t[5] = (_Float16)v1.y; t[6] = (_Float16)v1.z; t[7] = (_Float16)v1.w;
            a[ks] = t;
        }
    } else {
#pragma unroll
        for (int ks = 0; ks < 4; ks++) {
            half8 t;
#pragma unroll
            for (int j = 0; j < 8; j++) t[j] = (_Float16)0.f;
            a[ks] = t;
        }
    }
    const int rbase = m0 + g * 4;
    float ps[4] = {0.f, 0.f, 0.f, 0.f}, pd[4] = {0.f, 0.f, 0.f, 0.f};
#pragma unroll
    for (int nt = 0; nt < 16; nt++) {
        f32x4 acc = {0.f, 0.f, 0.f, 0.f};
#pragma unroll
        for (int ks = 0; ks < 4; ks++) {
            const half8 bfr = *reinterpret_cast<const half8*>(&w1sw[(size_t)((ks * 16 + nt) * 64 + lane) * 8]);
            acc = __builtin_amdgcn_mfma_f32_16x16x32_f16(a[ks], bfr, acc, 0, 0, 0);
        }
        const int col = nt * 16 + lm;
        const int q = col >> 6, cq = col & 63;
        const float av = a1s[col], dv = a1d[col];
#pragma unroll
        for (int r = 0; r < 4; r++) {
            const int row = rbase + r;
            if (row < N) qh1[(size_t)q * QS + (size_t)row * 64 + cq] = __float2half((float)acc[r]);
            ps[r] = fmaf((float)acc[r], av, ps[r]);
            pd[r] = fmaf((float)acc[r], dv, pd[r]);
        }
        if (nt & 1) {
#pragma unroll
            for (int off = 1; off <= 8; off <<= 1) {
#pragma unroll
                for (int r = 0; r < 4; r++) {
                    ps[r] += __shfl_xor(ps[r], off);
                    pd[r] += __shfl_xor(pd[r], off);
                }
            }
            if (lm == 0) {
                const int head = nt >> 1;
#pragma unroll
                for (int r = 0; r < 4; r++) {
                    const int row = rbase + r;
                    if (row < N) {
                        as1[row * HEADS + head] = ps[r];
                        ad1[row * HEADS + head] = pd[r];
                    }
                }
            }
#pragma unroll
            for (int r = 0; r < 4; r++) { ps[r] = 0.f; pd[r] = 0.f; }
        }
    }
}

// ---- K3: scatter with FUSED scan. Each block redundantly computes the full
//      2D exclusive scan of hist (L2-resident, ~160KB read) -> its own cursor
//      column; block 0 also writes bucket starts for k_bucket.
__global__ __launch_bounds__(256) void k_scatter2(
    const int* __restrict__ ei, int E, const int* __restrict__ hist,
    int* __restrict__ buck, int* __restrict__ bstart)
{
    __shared__ int cur[NB];
    __shared__ int bs[160];
    __shared__ int wbase[4];
    const int hb = blockIdx.x;
    const int tid = threadIdx.x;
    const int lane = tid & 63, wid = tid >> 6;
    int rp = 0;
    if (tid < NB) {
        const int4* hp = (const int4*)&hist[tid * HBLOCKS];
        int s = 0;
#pragma unroll 4
        for (int k = 0; k < 64; k++) {
            const int4 v = hp[k];
            s += (v.x + v.y) + (v.z + v.w);
            const int b4 = 4 * k;
            rp += ((b4 + 0) < hb ? v.x : 0) + ((b4 + 1) < hb ? v.y : 0)
                + ((b4 + 2) < hb ? v.z : 0) + ((b4 + 3) < hb ? v.w : 0);
        }
        bs[tid] = s;
    }
    __syncthreads();
    // exclusive scan of bs[0..NB)
    const int vin = (tid < NB) ? bs[tid] : 0;
    int v = vin;
#pragma unroll
    for (int off = 1; off < 64; off <<= 1) {
        const int u = __shfl_up(v, off, 64);
        if (lane >= off) v += u;
    }
    if (lane == 63) wbase[wid] = v;
    __syncthreads();
    if (tid < 64) {
        int w = (lane < 4) ? wbase[lane] : 0;
        const int orig = w;
#pragma unroll
        for (int off = 1; off < 4; off <<= 1) {
            const int u = __shfl_up(w, off, 64);
            if (lane >= off) w += u;
        }
        if (lane < 4) wbase[lane] = w - orig;
    }
    __syncthreads();
    if (tid < NB) {
        const int base = wbase[wid] + v - vin;   // exclusive global base of bucket tid
        cur[tid] = base + rp;
        if (hb == 0) bstart[tid] = base;
    }
    __syncthreads();
    const int ET = E + N;
    const int per = (ET + HBLOCKS - 1) / HBLOCKS;
    const int lo = hb * per;
    const int hi = (lo + per < ET) ? (lo + per) : ET;
    const int st = edge_stride(ei);
    for (int i = lo + tid; i < hi; i += 256) {
        int s, d;
        if (i < E) { s = ei[(size_t)st * i]; d = ei[(size_t)st * (E + i)]; }
        else       { s = i - E; d = i - E; }
        const int slot = atomicAdd(&cur[d >> BSHIFT], 1);
        buck[slot] = ((d & 127) << 16) | s;
    }
}

// ---- K4: per-bucket counting sort -> csr + rowptr (+ zero sentinels past ET).
__global__ __launch_bounds__(256) void k_bucket(
    const int* __restrict__ bstart, const int* __restrict__ buck, int ET,
    int* __restrict__ csr, int* __restrict__ rowptr)
{
    __shared__ int cnt[128];
    __shared__ int pfx[128];
    const int b = blockIdx.x;
    const int tid = threadIdx.x;
    const int start = bstart[b];
    const int end = (b == NB - 1) ? ET : bstart[b + 1];
    if (tid < 128) cnt[tid] = 0;
    __syncthreads();
    for (int i = start + tid; i < end; i += 256)
        atomicAdd(&cnt[buck[i] >> 16], 1);
    __syncthreads();
    if (tid < 128) pfx[tid] = cnt[tid];
    __syncthreads();
    for (int off = 1; off < 128; off <<= 1) {
        int u = 0;
        if (tid < 128 && tid >= off) u = pfx[tid - off];
        __syncthreads();
        if (tid < 128) pfx[tid] += u;
        __syncthreads();
    }
    if (tid < 128) {
        const int node = b * 128 + tid;
        const int ebase = start + pfx[tid] - cnt[tid];
        if (node < N) rowptr[node] = ebase;
        cnt[tid] = ebase;
    }
    if (b == NB - 1 && tid == 0) rowptr[N] = ET;
    if (b == NB - 1 && tid < 32) csr[ET + tid] = 0;   // sentinels: safe paired reads
    __syncthreads();
    for (int i = start + tid; i < end; i += 256) {
        const int val = buck[i];
        const int slot = atomicAdd(&cnt[val >> 16], 1);
        csr[slot] = val & 0xFFFF;
    }
}

// ---- K6: layer-1 aggregation. R1's proven loop body (8-edge unroll, per-lane
//      half2 gather, redundant per-16-lane weight exp, zero cross-lane ops)
//      on L2-RESIDENT quarter planes: block = 8 nodes x 32 lanes, quarter
//      hq = blockIdx&3 (block->XCD round-robin steering, validated R4/R5).
__global__ __launch_bounds__(256) void k_agg1(
    const int* __restrict__ rowptr, const int* __restrict__ csr,
    const __half* __restrict__ qh1,
    const float* __restrict__ as1, const float* __restrict__ ad1,
    const float* __restrict__ b1, __half* __restrict__ h1p)
{
    const int tid = threadIdx.x;
    const int l5 = tid & 31;                     // lane within node group
    const int sub = tid >> 5;                    // node slot 0..7
    const int hq = blockIdx.x & 3;               // quarter -> XCD steering
    const int n = (blockIdx.x >> 2) * 8 + sub;   // node
    const int cq = l5 * 2;                       // channel pair within quarter
    const int head = hq * 2 + (l5 >> 4);         // head for this lane's channels
    const float dv = ad1[n * HEADS + head];
    const int beg = rowptr[n], end = rowptr[n + 1];
    const __half* plane = qh1 + (size_t)hq * QS;
    float ax = 0.f, ay = 0.f, accw = 0.f;
    int e = beg;
    for (; e + 7 < end; e += 8) {
        int s[8];
        float w[8];
        float2 f[8];
#pragma unroll
        for (int j = 0; j < 8; j++) s[j] = csr[e + j];
#pragma unroll
        for (int j = 0; j < 8; j++) w[j] = __expf(lrelu(as1[s[j] * HEADS + head] + dv));
#pragma unroll
        for (int j = 0; j < 8; j++)
            f[j] = __half22float2(*reinterpret_cast<const __half2*>(&plane[(size_t)s[j] * 64 + cq]));
#pragma unroll
        for (int j = 0; j < 8; j++) {
            accw += w[j];
            ax = fmaf(w[j], f[j].x, ax);
            ay = fmaf(w[j], f[j].y, ay);
        }
    }
    for (; e + 3 < end; e += 4) {
        const int s0 = csr[e], s1 = csr[e + 1], s2 = csr[e + 2], s3 = csr[e + 3];
        const float w0 = __expf(lrelu(as1[s0 * HEADS + head] + dv));
        const float w1 = __expf(lrelu(as1[s1 * HEADS + head] + dv));
        const float w2 = __expf(lrelu(as1[s2 * HEADS + head] + dv));
        const float w3 = __expf(lrelu(as1[s3 * HEADS + head] + dv));
        const float2 f0 = __half22float2(*reinterpret_cast<const __half2*>(&plane[(size_t)s0 * 64 + cq]));
        const float2 f1 = __half22float2(*reinterpret_cast<const __half2*>(&plane[(size_t)s1 * 64 + cq]));
        const float2 f2 = __half22float2(*reinterpret_cast<const __half2*>(&plane[(size_t)s2 * 64 + cq]));
        const float2 f3 = __half22float2(*reinterpret_cast<const __half2*>(&plane[(size_t)s3 * 64 + cq]));
        accw += (w0 + w1) + (w2 + w3);
        ax = fmaf(w0, f0.x, ax); ay = fmaf(w0, f0.y, ay);
        ax = fmaf(w1, f1.x, ax); ay = fmaf(w1, f1.y, ay);
        ax = fmaf(w2, f2.x, ax); ay = fmaf(w2, f2.y, ay);
        ax = fmaf(w3, f3.x, ax); ay = fmaf(w3, f3.y, ay);
    }
    for (; e < end; e++) {
        const int s = csr[e];
        const float w = __expf(lrelu(as1[s * HEADS + head] + dv));
        const float2 f = __half22float2(*reinterpret_cast<const __half2*>(&plane[(size_t)s * 64 + cq]));
        accw += w;
        ax = fmaf(w, f.x, ax); ay = fmaf(w, f.y, ay);
    }
    const float inv = 1.f / accw;
    const int ch = hq * 64 + cq;
    float ox = ax * inv + b1[ch];
    float oy = ay * inv + b1[ch + 1];
    ox = (ox > 0.f) ? ox : (__expf(ox) - 1.f);
    oy = (oy > 0.f) ? oy : (__expf(oy) - 1.f);
    *reinterpret_cast<__half2*>(&h1p[(size_t)n * C1 + ch]) = __floats2half2_rn(ox, oy);
}

// ---- K7: h2 = h1p @ W2 via MFMA (NC=40 padded to 3x16 col tiles); fused as2/ad2.
//      h2h stored with row stride NCP=64 halves (128B = exactly one cache line).
__global__ __launch_bounds__(256) void k_gemm2_mfma(
    const __half* __restrict__ h1p, const _Float16* __restrict__ w2sw,
    const float* __restrict__ a2s, const float* __restrict__ a2d,
    __half* __restrict__ h2h, float* __restrict__ as2, float* __restrict__ ad2)
{
    const int lane = threadIdx.x & 63;
    const int wid = (blockIdx.x * 256 + threadIdx.x) >> 6;
    const int m0 = wid * 16;
    const int g = lane >> 4, lm = lane & 15;
    const int arow = m0 + lm;
    half8 a[8];
    if (arow < N) {
        const __half* hr = h1p + (size_t)arow * C1;
#pragma unroll
        for (int ks = 0; ks < 8; ks++)
            a[ks] = *reinterpret_cast<const half8*>(&hr[ks * 32 + g * 8]);
    } else {
#pragma unroll
        for (int ks = 0; ks < 8; ks++) {
            half8 t;
#pragma unroll
            for (int j = 0; j < 8; j++) t[j] = (_Float16)0.f;
            a[ks] = t;
        }
    }
    f32x4 acc[3];
#pragma unroll
    for (int nt = 0; nt < 3; nt++) acc[nt] = (f32x4){0.f, 0.f, 0.f, 0.f};
#pragma unroll
    for (int ks = 0; ks < 8; ks++) {
#pragma unroll
        for (int nt = 0; nt < 3; nt++) {
            const half8 bfr = *reinterpret_cast<const half8*>(&w2sw[(size_t)((ks * 3 + nt) * 64 + lane) * 8]);
            acc[nt] = __builtin_amdgcn_mfma_f32_16x16x32_f16(a[ks], bfr, acc[nt], 0, 0, 0);
        }
    }
    const int rbase = m0 + g * 4;
    float av[3], dvv[3];
#pragma unroll
    for (int nt = 0; nt < 3; nt++) {
        const int col = nt * 16 + lm;
        av[nt]  = (col < NC) ? a2s[col] : 0.f;
        dvv[nt] = (col < NC) ? a2d[col] : 0.f;
    }
#pragma unroll
    for (int r = 0; r < 4; r++) {
        const int row = rbase + r;
        float ps = 0.f, pd = 0.f;
#pragma unroll
        for (int nt = 0; nt < 3; nt++) {
            const float v = (float)acc[nt][r];
            const int col = nt * 16 + lm;
            if (row < N && col < NC) h2h[(size_t)row * NCP + col] = __float2half(v);
            ps = fmaf(v, av[nt], ps);
            pd = fmaf(v, dvv[nt], pd);
        }
#pragma unroll
        for (int off = 1; off <= 8; off <<= 1) {
            ps += __shfl_xor(ps, off);
            pd += __shfl_xor(pd, off);
        }
        if (lm == 0 && row < N) { as2[row] = ps; ad2[row] = pd; }
    }
}

// ---- K8: layer-2 aggregation + bias + log_softmax. One wave/node, unroll 8.
//      h2h padded to one line/row and fully L2-resident (2.56 MB).
__global__ __launch_bounds__(256) void k_agg2(
    const int* __restrict__ rowptr, const int* __restrict__ csr,
    const __half* __restrict__ h2h, const float* __restrict__ as2,
    const float* __restrict__ ad2, const float* __restrict__ b2,
    float* __restrict__ out)
{
    const int lane = threadIdx.x & 63;
    const int n = (blockIdx.x * blockDim.x + threadIdx.x) >> 6;
    const int c = lane;
    const int cc = (c < NC) ? c : (NC - 1);
    const float adv = ad2[n];
    const int beg = rowptr[n], end = rowptr[n + 1];
    float acc = 0.f, accw = 0.f;
    int e = beg;
    for (; e + 7 < end; e += 8) {
        int s[8];
        float w[8], g[8];
#pragma unroll
        for (int j = 0; j < 8; j++) s[j] = csr[e + j];
#pragma unroll
        for (int j = 0; j < 8; j++) w[j] = __expf(lrelu(as2[s[j]] + adv));
#pragma unroll
        for (int j = 0; j < 8; j++) g[j] = __half2float(h2h[(size_t)s[j] * NCP + cc]);
#pragma unroll
        for (int j = 0; j < 8; j++) {
            accw += w[j];
            acc = fmaf(w[j], g[j], acc);
        }
    }
    for (; e + 3 < end; e += 4) {
        const int s0 = csr[e], s1 = csr[e + 1], s2 = csr[e + 2], s3 = csr[e + 3];
        const float w0 = __expf(lrelu(as2[s0] + adv));
        const float w1 = __expf(lrelu(as2[s1] + adv));
        const float w2 = __expf(lrelu(as2[s2] + adv));
        const float w3 = __expf(lrelu(as2[s3] + adv));
        const float g0 = __half2float(h2h[(size_t)s0 * NCP + cc]);
        const float g1 = __half2float(h2h[(size_t)s1 * NCP + cc]);
        const float g2 = __half2float(h2h[(size_t)s2 * NCP + cc]);
        const float g3 = __half2float(h2h[(size_t)s3 * NCP + cc]);
        accw += (w0 + w1) + (w2 + w3);
        acc = fmaf(w0, g0, acc);
        acc = fmaf(w1, g1, acc);
        acc = fmaf(w2, g2, acc);
        acc = fmaf(w3, g3, acc);
    }
    for (; e < end; e++) {
        const int s = csr[e];
        const float w = __expf(lrelu(as2[s] + adv));
        accw += w;
        acc = fmaf(w, __half2float(h2h[(size_t)s * NCP + cc]), acc);
    }
    const float v = acc / accw + b2[cc];
    float m = (c < NC) ? v : -1e30f;
#pragma unroll
    for (int off = 32; off >= 1; off >>= 1) m = fmaxf(m, __shfl_xor(m, off));
    float S = (c < NC) ? __expf(v - m) : 0.f;
#pragma unroll
    for (int off = 32; off >= 1; off >>= 1) S += __shfl_xor(S, off);
    if (c < NC) out[(size_t)n * NC + c] = v - m - logf(S);
}

extern "C" void kernel_launch(void* const* d_in, const int* in_sizes, int n_in,
                              void* d_out, int out_size, void* d_ws, size_t ws_size,
                              hipStream_t stream)
{
    const float* x   = (const float*)d_in[0];
    const int*   ei  = (const int*)d_in[1];
    const float* W1  = (const float*)d_in[2];
    const float* a1s = (const float*)d_in[3];
    const float* a1d = (const float*)d_in[4];
    const float* b1  = (const float*)d_in[5];
    const float* W2  = (const float*)d_in[6];
    const float* a2s = (const float*)d_in[7];
    const float* a2d = (const float*)d_in[8];
    const float* b2  = (const float*)d_in[9];
    float* out = (float*)d_out;

    const int E  = in_sizes[1] / 2;
    const int ET = E + N;

    auto align64 = [](size_t v) { return (v + 63) & ~(size_t)63; };
    char* ws = (char*)d_ws;
    size_t off = 0;
    _Float16* w1sw = (_Float16*)(ws + off); off = align64(off + (size_t)4096 * 8 * 2);
    _Float16* w2sw = (_Float16*)(ws + off); off = align64(off + (size_t)1536 * 8 * 2);
    __half* qh1 = (__half*)(ws + off); off = align64(off + (size_t)N * C1 * 2);   // 4 quarter planes
    __half* h1p = (__half*)(ws + off); off = align64(off + (size_t)N * C1 * 2);
    __half* h2h = (__half*)(ws + off); off = align64(off + (size_t)N * NCP * 2);
    float* as1 = (float*)(ws + off); off = align64(off + (size_t)N * HEADS * 4);
    float* ad1 = (float*)(ws + off); off = align64(off + (size_t)N * HEADS * 4);
    float* as2 = (float*)(ws + off); off = align64(off + (size_t)N * 4);
    float* ad2 = (float*)(ws + off); off = align64(off + (size_t)N * 4);
    int* hist   = (int*)(ws + off); off = align64(off + (size_t)HM * 4);
    int* bstart = (int*)(ws + off); off = align64(off + (size_t)NB * 4);
    int* buck   = (int*)(ws + off); off = align64(off + (size_t)ET * 4);
    int* rowptr = (int*)(ws + off); off = align64(off + (size_t)(N + 1) * 4);
    int* csr    = (int*)(ws + off); off = align64(off + (size_t)ET * 4 + 128);

    k_misc<<<PREPW_BLOCKS + W2PW_BLOCKS + HBLOCKS, 256, 0, stream>>>(W1, w1sw, W2, w2sw, ei, E, hist);
    k_gemm1_mfma<<<313, 256, 0, stream>>>(x, w1sw, a1s, a1d, qh1, as1, ad1);
    k_scatter2<<<HBLOCKS, 256, 0, stream>>>(ei, E, hist, buck, bstart);
    k_bucket<<<NB, 256, 0, stream>>>(bstart, buck, ET, csr, rowptr);
    k_agg1<<<N / 2, 256, 0, stream>>>(rowptr, csr, qh1, as1, ad1, b1, h1p);
    k_gemm2_mfma<<<313, 256, 0, stream>>>(h1p, w2sw, a2s, a2d, h2h, as2, ad2);
    k_agg2<<<5000, 256, 0, stream>>>(rowptr, csr, h2h, as2, ad2, b2, out);
}

// Round 8
// 198.859 us; speedup vs baseline: 1.3315x; 1.0274x over previous
//
#include <hip/hip_runtime.h>
#include <hip/hip_fp16.h>
#include <math.h>

#define N 20000
#define F 128
#define C1 256   // HEADS*HIDDEN
#define HEADS 8
#define HID 32
#define NC 40
#define NCP 64   // padded h2h row stride (1 cache line)
#define NEG 0.2f

#define BSHIFT 7
#define NB 157        // buckets of 128 nodes
#define HBLOCKS 256
#define HM (NB * HBLOCKS)

#define PREPW_BLOCKS 16
#define W2PW_BLOCKS 6   // 24 frags * 64 lanes = 1536 half8 slots

#define QS ((size_t)N * 64)   // quarter-plane element stride

typedef _Float16 half8 __attribute__((ext_vector_type(8)));
typedef float f32x4 __attribute__((ext_vector_type(4)));

__device__ __forceinline__ int edge_stride(const int* ei) {
    return (ei[1] == 0 && ei[3] == 0 && ei[5] == 0 && ei[7] == 0 && ei[9] == 0) ? 2 : 1;
}

__device__ __forceinline__ float lrelu(float v) { return v > 0.f ? v : NEG * v; }

// ---- K0: fused prep (W1 swizzle + W2 swizzle) + bucket histogram (LDS atomics only)
__global__ __launch_bounds__(256) void k_misc(
    const float* __restrict__ W1, _Float16* __restrict__ w1sw,
    const float* __restrict__ W2, _Float16* __restrict__ w2sw,
    const int* __restrict__ ei, int E, int* __restrict__ hist)
{
    const int b = blockIdx.x;
    const int tid = threadIdx.x;
    if (b < PREPW_BLOCKS) {
        const int slot = b * 256 + tid;
        const int lane = slot & 63;
        const int tile = slot >> 6;
        const int nt = tile & 15, ks = tile >> 4;
        const int n = nt * 16 + (lane & 15);
        const int k0 = ks * 32 + (lane >> 4) * 8;
        half8 tmp;
#pragma unroll
        for (int j = 0; j < 8; j++) tmp[j] = (_Float16)W1[(k0 + j) * C1 + n];
        *reinterpret_cast<half8*>(&w1sw[(size_t)slot * 8]) = tmp;
    } else if (b < PREPW_BLOCKS + W2PW_BLOCKS) {
        const int slot = (b - PREPW_BLOCKS) * 256 + tid;   // 0..1535
        const int lane = slot & 63;
        const int f = slot >> 6;          // 0..23
        const int nt = f % 3, ks = f / 3;
        const int n = nt * 16 + (lane & 15);
        const int k0 = ks * 32 + (lane >> 4) * 8;
        half8 tmp;
#pragma unroll
        for (int j = 0; j < 8; j++)
            tmp[j] = (n < NC) ? (_Float16)W2[(k0 + j) * NC + n] : (_Float16)0.f;
        *reinterpret_cast<half8*>(&w2sw[(size_t)slot * 8]) = tmp;
    } else {
        __shared__ int hcnt[NB];
        const int hb = b - PREPW_BLOCKS - W2PW_BLOCKS;
        if (tid < NB) hcnt[tid] = 0;
        __syncthreads();
        const int ET = E + N;
        const int per = (ET + HBLOCKS - 1) / HBLOCKS;
        const int lo = hb * per;
        const int hi = (lo + per < ET) ? (lo + per) : ET;
        const int st = edge_stride(ei);
        for (int i = lo + tid; i < hi; i += 256) {
            const int d = (i < E) ? ei[(size_t)st * (E + i)] : (i - E);
            atomicAdd(&hcnt[d >> BSHIFT], 1);
        }
        __syncthreads();
        if (tid < NB) hist[tid * HBLOCKS + hb] = hcnt[tid];
    }
}

// ---- K1: h1 = x @ W1 via MFMA; h1 written as FOUR 64-ch quarter planes
//      (each 2.56 MB -> L2-resident per XCD with blockIdx&3 steering in k_agg1).
__global__ __launch_bounds__(256) void k_gemm1_mfma(
    const float* __restrict__ x, const _Float16* __restrict__ w1sw,
    const float* __restrict__ a1s, const float* __restrict__ a1d,
    __half* __restrict__ qh1,
    float* __restrict__ as1, float* __restrict__ ad1)
{
    const int lane = threadIdx.x & 63;
    const int wid = (blockIdx.x * 256 + threadIdx.x) >> 6;
    const int m0 = wid * 16;
    const int g = lane >> 4, lm = lane & 15;
    const int arow = m0 + lm;
    half8 a[4];
    if (arow < N) {
        const float* xr = x + (size_t)arow * F;
#pragma unroll
        for (int ks = 0; ks < 4; ks++) {
            const float4 v0 = *reinterpret_cast<const float4*>(&xr[ks * 32 + g * 8]);
            const float4 v1 = *reinterpret_cast<const float4*>(&xr[ks * 32 + g * 8 + 4]);
            half8 t;
            t[0] = (_Float16)v0.x; t[1] = (_Float16)v0.y; t[2] = (_Float16)v0.z; t[3] = (_Float16)v0.w;
            t[4] = (_Float16)v1.x; t[5] = (_Float16)v1.y; t[6] = (_Float16)v1.z; t[7] = (_Float16)v1.w;
            a[ks] = t;
        }
    } else {
#pragma unroll
        for (int ks = 0; ks < 4; ks++) {
            half8 t;
#pragma unroll
            for (int j = 0; j < 8; j++) t[j] = (_Float16)0.f;
            a[ks] = t;
        }
    }
    const int rbase = m0 + g * 4;
    float ps[4] = {0.f, 0.f, 0.f, 0.f}, pd[4] = {0.f, 0.f, 0.f, 0.f};
#pragma unroll
    for (int nt = 0; nt < 16; nt++) {
        f32x4 acc = {0.f, 0.f, 0.f, 0.f};
#pragma unroll
        for (int ks = 0; ks < 4; ks++) {
            const half8 bfr = *reinterpret_cast<const half8*>(&w1sw[(size_t)((ks * 16 + nt) * 64 + lane) * 8]);
            acc = __builtin_amdgcn_mfma_f32_16x16x32_f16(a[ks], bfr, acc, 0, 0, 0);
        }
        const int col = nt * 16 + lm;
        const int q = col >> 6, cq = col & 63;
        const float av = a1s[col], dv = a1d[col];
#pragma unroll
        for (int r = 0; r < 4; r++) {
            const int row = rbase + r;
            if (row < N) qh1[(size_t)q * QS + (size_t)row * 64 + cq] = __float2half((float)acc[r]);
            ps[r] = fmaf((float)acc[r], av, ps[r]);
            pd[r] = fmaf((float)acc[r], dv, pd[r]);
        }
        if (nt & 1) {
#pragma unroll
            for (int off = 1; off <= 8; off <<= 1) {
#pragma unroll
                for (int r = 0; r < 4; r++) {
                    ps[r] += __shfl_xor(ps[r], off);
                    pd[r] += __shfl_xor(pd[r], off);
                }
            }
            if (lm == 0) {
                const int head = nt >> 1;
#pragma unroll
                for (int r = 0; r < 4; r++) {
                    const int row = rbase + r;
                    if (row < N) {
                        as1[row * HEADS + head] = ps[r];
                        ad1[row * HEADS + head] = pd[r];
                    }
                }
            }
#pragma unroll
            for (int r = 0; r < 4; r++) { ps[r] = 0.f; pd[r] = 0.f; }
        }
    }
}

// ---- K3: scatter with FUSED scan. Each block redundantly computes the full
//      2D exclusive scan of hist (L2-resident, ~160KB read) -> its own cursor
//      column; block 0 also writes bucket starts for k_bucket.
__global__ __launch_bounds__(256) void k_scatter2(
    const int* __restrict__ ei, int E, const int* __restrict__ hist,
    int* __restrict__ buck, int* __restrict__ bstart)
{
    __shared__ int cur[NB];
    __shared__ int bs[160];
    __shared__ int wbase[4];
    const int hb = blockIdx.x;
    const int tid = threadIdx.x;
    const int lane = tid & 63, wid = tid >> 6;
    int rp = 0;
    if (tid < NB) {
        const int4* hp = (const int4*)&hist[tid * HBLOCKS];
        int s = 0;
#pragma unroll 4
        for (int k = 0; k < 64; k++) {
            const int4 v = hp[k];
            s += (v.x + v.y) + (v.z + v.w);
            const int b4 = 4 * k;
            rp += ((b4 + 0) < hb ? v.x : 0) + ((b4 + 1) < hb ? v.y : 0)
                + ((b4 + 2) < hb ? v.z : 0) + ((b4 + 3) < hb ? v.w : 0);
        }
        bs[tid] = s;
    }
    __syncthreads();
    // exclusive scan of bs[0..NB)
    const int vin = (tid < NB) ? bs[tid] : 0;
    int v = vin;
#pragma unroll
    for (int off = 1; off < 64; off <<= 1) {
        const int u = __shfl_up(v, off, 64);
        if (lane >= off) v += u;
    }
    if (lane == 63) wbase[wid] = v;
    __syncthreads();
    if (tid < 64) {
        int w = (lane < 4) ? wbase[lane] : 0;
        const int orig = w;
#pragma unroll
        for (int off = 1; off < 4; off <<= 1) {
            const int u = __shfl_up(w, off, 64);
            if (lane >= off) w += u;
        }
        if (lane < 4) wbase[lane] = w - orig;
    }
    __syncthreads();
    if (tid < NB) {
        const int base = wbase[wid] + v - vin;   // exclusive global base of bucket tid
        cur[tid] = base + rp;
        if (hb == 0) bstart[tid] = base;
    }
    __syncthreads();
    const int ET = E + N;
    const int per = (ET + HBLOCKS - 1) / HBLOCKS;
    const int lo = hb * per;
    const int hi = (lo + per < ET) ? (lo + per) : ET;
    const int st = edge_stride(ei);
    for (int i = lo + tid; i < hi; i += 256) {
        int s, d;
        if (i < E) { s = ei[(size_t)st * i]; d = ei[(size_t)st * (E + i)]; }
        else       { s = i - E; d = i - E; }
        const int slot = atomicAdd(&cur[d >> BSHIFT], 1);
        buck[slot] = ((d & 127) << 16) | s;
    }
}

// ---- K4: per-bucket counting sort -> csr + rowptr (+ 64 zero sentinels past ET).
__global__ __launch_bounds__(256) void k_bucket(
    const int* __restrict__ bstart, const int* __restrict__ buck, int ET,
    int* __restrict__ csr, int* __restrict__ rowptr)
{
    __shared__ int cnt[128];
    __shared__ int pfx[128];
    const int b = blockIdx.x;
    const int tid = threadIdx.x;
    const int start = bstart[b];
    const int end = (b == NB - 1) ? ET : bstart[b + 1];
    if (tid < 128) cnt[tid] = 0;
    __syncthreads();
    for (int i = start + tid; i < end; i += 256)
        atomicAdd(&cnt[buck[i] >> 16], 1);
    __syncthreads();
    if (tid < 128) pfx[tid] = cnt[tid];
    __syncthreads();
    for (int off = 1; off < 128; off <<= 1) {
        int u = 0;
        if (tid < 128 && tid >= off) u = pfx[tid - off];
        __syncthreads();
        if (tid < 128) pfx[tid] += u;
        __syncthreads();
    }
    if (tid < 128) {
        const int node = b * 128 + tid;
        const int ebase = start + pfx[tid] - cnt[tid];
        if (node < N) rowptr[node] = ebase;
        cnt[tid] = ebase;
    }
    if (b == NB - 1 && tid == 0) rowptr[N] = ET;
    if (b == NB - 1 && tid < 64) csr[ET + tid] = 0;   // sentinels: safe 64-wide producer reads
    __syncthreads();
    for (int i = start + tid; i < end; i += 256) {
        const int val = buck[i];
        const int slot = atomicAdd(&cnt[val >> 16], 1);
        csr[slot] = val & 0xFFFF;
    }
}

// ---- K6: layer-1 aggregation on L2-resident quarter planes (R7 structure) with
//      LDS-staged weights: per 32-edge burst, phase A = each lane computes the
//      2 quarter-head weights for ONE edge (2 exps/lane vs 32 redundant),
//      phase B = broadcast float4 LDS reads + 4 independent gathers in flight.
//      Same-wave DS write->read needs no barrier (R3-validated). w=0 padding
//      kills all tail divergence.
__global__ __launch_bounds__(256) void k_agg1(
    const int* __restrict__ rowptr, const int* __restrict__ csr,
    const __half* __restrict__ qh1,
    const float* __restrict__ as1, const float* __restrict__ ad1,
    const float* __restrict__ b1, __half* __restrict__ h1p)
{
    __shared__ __align__(16) float wlds[8][2][36];
    const int tid = threadIdx.x;
    const int l5 = tid & 31;                     // lane within node group
    const int sub = tid >> 5;                    // node slot 0..7
    const int hq = blockIdx.x & 3;               // quarter -> XCD steering
    const int n = (blockIdx.x >> 2) * 8 + sub;   // node
    const int cq = l5 * 2;                       // channel pair within quarter
    const int hsel = l5 >> 4;                    // consumer head-sub (0/1)
    const float2 dv2 = *reinterpret_cast<const float2*>(&ad1[n * HEADS + hq * 2]);
    const int beg = rowptr[n], end = rowptr[n + 1];
    const __half* plane = qh1 + (size_t)hq * QS;
    float* w0 = wlds[sub][0];
    float* w1 = wlds[sub][1];
    const float* wc = wlds[sub][hsel];
    float ax = 0.f, ay = 0.f, accw = 0.f;
    for (int cs = beg; cs < end; cs += 32) {
        const int m = end - cs;
        // phase A: one edge per lane, both heads (2 exps); zero-pad past m
        {
            const int s = csr[cs + l5];          // sentinel-safe
            const float2 a2 = *reinterpret_cast<const float2*>(&as1[s * HEADS + hq * 2]);
            const bool ok = l5 < m;
            w0[l5] = ok ? __expf(lrelu(a2.x + dv2.x)) : 0.f;
            w1[l5] = ok ? __expf(lrelu(a2.y + dv2.y)) : 0.f;
        }
        // phase B: consume 4 edges at a time (broadcast LDS float4 + 4 gathers)
        const int mm4 = (m < 32) ? ((m + 3) & ~3) : 32;
        for (int j0 = 0; j0 < mm4; j0 += 4) {
            const int sA = csr[cs + j0];
            const int sB = csr[cs + j0 + 1];
            const int sC = csr[cs + j0 + 2];
            const int sD = csr[cs + j0 + 3];
            const float4 wf = *reinterpret_cast<const float4*>(&wc[j0]);
            const float2 gA = __half22float2(*reinterpret_cast<const __half2*>(&plane[(size_t)sA * 64 + cq]));
            const float2 gB = __half22float2(*reinterpret_cast<const __half2*>(&plane[(size_t)sB * 64 + cq]));
            const float2 gC = __half22float2(*reinterpret_cast<const __half2*>(&plane[(size_t)sC * 64 + cq]));
            const float2 gD = __half22float2(*reinterpret_cast<const __half2*>(&plane[(size_t)sD * 64 + cq]));
            accw += (wf.x + wf.y) + (wf.z + wf.w);
            ax = fmaf(wf.x, gA.x, ax); ay = fmaf(wf.x, gA.y, ay);
            ax = fmaf(wf.y, gB.x, ax); ay = fmaf(wf.y, gB.y, ay);
            ax = fmaf(wf.z, gC.x, ax); ay = fmaf(wf.z, gC.y, ay);
            ax = fmaf(wf.w, gD.x, ax); ay = fmaf(wf.w, gD.y, ay);
        }
    }
    const float inv = 1.f / accw;
    const int ch = hq * 64 + cq;
    float ox = ax * inv + b1[ch];
    float oy = ay * inv + b1[ch + 1];
    ox = (ox > 0.f) ? ox : (__expf(ox) - 1.f);
    oy = (oy > 0.f) ? oy : (__expf(oy) - 1.f);
    *reinterpret_cast<__half2*>(&h1p[(size_t)n * C1 + ch]) = __floats2half2_rn(ox, oy);
}

// ---- K7: h2 = h1p @ W2 via MFMA (NC=40 padded to 3x16 col tiles); fused as2/ad2.
//      h2h stored with row stride NCP=64 halves (128B = exactly one cache line).
__global__ __launch_bounds__(256) void k_gemm2_mfma(
    const __half* __restrict__ h1p, const _Float16* __restrict__ w2sw,
    const float* __restrict__ a2s, const float* __restrict__ a2d,
    __half* __restrict__ h2h, float* __restrict__ as2, float* __restrict__ ad2)
{
    const int lane = threadIdx.x & 63;
    const int wid = (blockIdx.x * 256 + threadIdx.x) >> 6;
    const int m0 = wid * 16;
    const int g = lane >> 4, lm = lane & 15;
    const int arow = m0 + lm;
    half8 a[8];
    if (arow < N) {
        const __half* hr = h1p + (size_t)arow * C1;
#pragma unroll
        for (int ks = 0; ks < 8; ks++)
            a[ks] = *reinterpret_cast<const half8*>(&hr[ks * 32 + g * 8]);
    } else {
#pragma unroll
        for (int ks = 0; ks < 8; ks++) {
            half8 t;
#pragma unroll
            for (int j = 0; j < 8; j++) t[j] = (_Float16)0.f;
            a[ks] = t;
        }
    }
    f32x4 acc[3];
#pragma unroll
    for (int nt = 0; nt < 3; nt++) acc[nt] = (f32x4){0.f, 0.f, 0.f, 0.f};
#pragma unroll
    for (int ks = 0; ks < 8; ks++) {
#pragma unroll
        for (int nt = 0; nt < 3; nt++) {
            const half8 bfr = *reinterpret_cast<const half8*>(&w2sw[(size_t)((ks * 3 + nt) * 64 + lane) * 8]);
            acc[nt] = __builtin_amdgcn_mfma_f32_16x16x32_f16(a[ks], bfr, acc[nt], 0, 0, 0);
        }
    }
    const int rbase = m0 + g * 4;
    float av[3], dvv[3];
#pragma unroll
    for (int nt = 0; nt < 3; nt++) {
        const int col = nt * 16 + lm;
        av[nt]  = (col < NC) ? a2s[col] : 0.f;
        dvv[nt] = (col < NC) ? a2d[col] : 0.f;
    }
#pragma unroll
    for (int r = 0; r < 4; r++) {
        const int row = rbase + r;
        float ps = 0.f, pd = 0.f;
#pragma unroll
        for (int nt = 0; nt < 3; nt++) {
            const float v = (float)acc[nt][r];
            const int col = nt * 16 + lm;
            if (row < N && col < NC) h2h[(size_t)row * NCP + col] = __float2half(v);
            ps = fmaf(v, av[nt], ps);
            pd = fmaf(v, dvv[nt], pd);
        }
#pragma unroll
        for (int off = 1; off <= 8; off <<= 1) {
            ps += __shfl_xor(ps, off);
            pd += __shfl_xor(pd, off);
        }
        if (lm == 0 && row < N) { as2[row] = ps; ad2[row] = pd; }
    }
}

// ---- K8: layer-2 aggregation + bias + log_softmax. One wave/node.
//      LDS-staged weights: per 64-edge burst, ONE exp per lane (vs 64x redundant),
//      then broadcast float4 LDS reads in phase B. h2h L2-resident (2.56 MB).
__global__ __launch_bounds__(256) void k_agg2(
    const int* __restrict__ rowptr, const int* __restrict__ csr,
    const __half* __restrict__ h2h, const float* __restrict__ as2,
    const float* __restrict__ ad2, const float* __restrict__ b2,
    float* __restrict__ out)
{
    __shared__ __align__(16) float wl[4][68];
    const int lane = threadIdx.x & 63;
    const int wv = threadIdx.x >> 6;
    const int n = (blockIdx.x * blockDim.x + threadIdx.x) >> 6;
    const int c = lane;
    const int cc = (c < NC) ? c : (NC - 1);
    const float adv = ad2[n];
    const int beg = rowptr[n], end = rowptr[n + 1];
    float* w = wl[wv];
    float acc = 0.f, accw = 0.f;
    for (int cs = beg; cs < end; cs += 64) {
        const int m = end - cs;
        // phase A: one exp per lane (64 edges per burst); zero-pad past m
        {
            const int s = csr[cs + lane];        // sentinel-safe (64 zeros past ET)
            w[lane] = (lane < m) ? __expf(lrelu(as2[s] + adv)) : 0.f;
        }
        // phase B: 4 edges at a time
        const int mm4 = (m < 64) ? ((m + 3) & ~3) : 64;
        for (int j0 = 0; j0 < mm4; j0 += 4) {
            const int s0 = csr[cs + j0];
            const int s1 = csr[cs + j0 + 1];
            const int s2 = csr[cs + j0 + 2];
            const int s3 = csr[cs + j0 + 3];
            const float4 wf = *reinterpret_cast<const float4*>(&w[j0]);
            const float g0 = __half2float(h2h[(size_t)s0 * NCP + cc]);
            const float g1 = __half2float(h2h[(size_t)s1 * NCP + cc]);
            const float g2 = __half2float(h2h[(size_t)s2 * NCP + cc]);
            const float g3 = __half2float(h2h[(size_t)s3 * NCP + cc]);
            accw += (wf.x + wf.y) + (wf.z + wf.w);
            acc = fmaf(wf.x, g0, acc);
            acc = fmaf(wf.y, g1, acc);
            acc = fmaf(wf.z, g2, acc);
            acc = fmaf(wf.w, g3, acc);
        }
    }
    const float v = acc / accw + b2[cc];
    float m = (c < NC) ? v : -1e30f;
#pragma unroll
    for (int off = 32; off >= 1; off >>= 1) m = fmaxf(m, __shfl_xor(m, off));
    float S = (c < NC) ? __expf(v - m) : 0.f;
#pragma unroll
    for (int off = 32; off >= 1; off >>= 1) S += __shfl_xor(S, off);
    if (c < NC) out[(size_t)n * NC + c] = v - m - logf(S);
}

extern "C" void kernel_launch(void* const* d_in, const int* in_sizes, int n_in,
                              void* d_out, int out_size, void* d_ws, size_t ws_size,
                              hipStream_t stream)
{
    const float* x   = (const float*)d_in[0];
    const int*   ei  = (const int*)d_in[1];
    const float* W1  = (const float*)d_in[2];
    const float* a1s = (const float*)d_in[3];
    const float* a1d = (const float*)d_in[4];
    const float* b1  = (const float*)d_in[5];
    const float* W2  = (const float*)d_in[6];
    const float* a2s = (const float*)d_in[7];
    const float* a2d = (const float*)d_in[8];
    const float* b2  = (const float*)d_in[9];
    float* out = (float*)d_out;

    const int E  = in_sizes[1] / 2;
    const int ET = E + N;

    auto align64 = [](size_t v) { return (v + 63) & ~(size_t)63; };
    char* ws = (char*)d_ws;
    size_t off = 0;
    _Float16* w1sw = (_Float16*)(ws + off); off = align64(off + (size_t)4096 * 8 * 2);
    _Float16* w2sw = (_Float16*)(ws + off); off = align64(off + (size_t)1536 * 8 * 2);
    __half* qh1 = (__half*)(ws + off); off = align64(off + (size_t)N * C1 * 2);   // 4 quarter planes
    __half* h1p = (__half*)(ws + off); off = align64(off + (size_t)N * C1 * 2);
    __half* h2h = (__half*)(ws + off); off = align64(off + (size_t)N * NCP * 2);
    float* as1 = (float*)(ws + off); off = align64(off + (size_t)N * HEADS * 4);
    float* ad1 = (float*)(ws + off); off = align64(off + (size_t)N * HEADS * 4);
    float* as2 = (float*)(ws + off); off = align64(off + (size_t)N * 4);
    float* ad2 = (float*)(ws + off); off = align64(off + (size_t)N * 4);
    int* hist   = (int*)(ws + off); off = align64(off + (size_t)HM * 4);
    int* bstart = (int*)(ws + off); off = align64(off + (size_t)NB * 4);
    int* buck   = (int*)(ws + off); off = align64(off + (size_t)ET * 4);
    int* rowptr = (int*)(ws + off); off = align64(off + (size_t)(N + 1) * 4);
    int* csr    = (int*)(ws + off); off = align64(off + (size_t)ET * 4 + 256);

    k_misc<<<PREPW_BLOCKS + W2PW_BLOCKS + HBLOCKS, 256, 0, stream>>>(W1, w1sw, W2, w2sw, ei, E, hist);
    k_gemm1_mfma<<<313, 256, 0, stream>>>(x, w1sw, a1s, a1d, qh1, as1, ad1);
    k_scatter2<<<HBLOCKS, 256, 0, stream>>>(ei, E, hist, buck, bstart);
    k_bucket<<<NB, 256, 0, stream>>>(bstart, buck, ET, csr, rowptr);
    k_agg1<<<N / 2, 256, 0, stream>>>(rowptr, csr, qh1, as1, ad1, b1, h1p);
    k_gemm2_mfma<<<313, 256, 0, stream>>>(h1p, w2sw, a2s, a2d, h2h, as2, ad2);
    k_agg2<<<5000, 256, 0, stream>>>(rowptr, csr, h2h, as2, ad2, b2, out);
}

// Round 9
// 183.376 us; speedup vs baseline: 1.4439x; 1.0844x over previous
//
#include <hip/hip_runtime.h>
#include <hip/hip_fp16.h>
#include <math.h>

#define N 20000
#define F 128
#define C1 256   // HEADS*HIDDEN
#define HEADS 8
#define HID 32
#define NC 40
#define NCP 64   // padded h2h row stride (1 cache line)
#define NEG 0.2f

#define BSHIFT 7
#define NB 157        // buckets of 128 nodes
#define HBLOCKS 256
#define HM (NB * HBLOCKS)

#define PREPW_BLOCKS 16
#define W2PW_BLOCKS 6   // 24 frags * 64 lanes = 1536 half8 slots

#define QS ((size_t)N * 64)   // quarter-plane element stride

typedef _Float16 half8 __attribute__((ext_vector_type(8)));
typedef float f32x4 __attribute__((ext_vector_type(4)));

__device__ __forceinline__ int edge_stride(const int* ei) {
    return (ei[1] == 0 && ei[3] == 0 && ei[5] == 0 && ei[7] == 0 && ei[9] == 0) ? 2 : 1;
}

__device__ __forceinline__ float lrelu(float v) { return v > 0.f ? v : NEG * v; }

// ---- K0: fused prep (W1 swizzle + W2 swizzle) + bucket histogram (LDS atomics only)
__global__ __launch_bounds__(256) void k_misc(
    const float* __restrict__ W1, _Float16* __restrict__ w1sw,
    const float* __restrict__ W2, _Float16* __restrict__ w2sw,
    const int* __restrict__ ei, int E, int* __restrict__ hist)
{
    const int b = blockIdx.x;
    const int tid = threadIdx.x;
    if (b < PREPW_BLOCKS) {
        const int slot = b * 256 + tid;
        const int lane = slot & 63;
        const int tile = slot >> 6;
        const int nt = tile & 15, ks = tile >> 4;
        const int n = nt * 16 + (lane & 15);
        const int k0 = ks * 32 + (lane >> 4) * 8;
        half8 tmp;
#pragma unroll
        for (int j = 0; j < 8; j++) tmp[j] = (_Float16)W1[(k0 + j) * C1 + n];
        *reinterpret_cast<half8*>(&w1sw[(size_t)slot * 8]) = tmp;
    } else if (b < PREPW_BLOCKS + W2PW_BLOCKS) {
        const int slot = (b - PREPW_BLOCKS) * 256 + tid;   // 0..1535
        const int lane = slot & 63;
        const int f = slot >> 6;          // 0..23
        const int nt = f % 3, ks = f / 3;
        const int n = nt * 16 + (lane & 15);
        const int k0 = ks * 32 + (lane >> 4) * 8;
        half8 tmp;
#pragma unroll
        for (int j = 0; j < 8; j++)
            tmp[j] = (n < NC) ? (_Float16)W2[(k0 + j) * NC + n] : (_Float16)0.f;
        *reinterpret_cast<half8*>(&w2sw[(size_t)slot * 8]) = tmp;
    } else {
        __shared__ int hcnt[NB];
        const int hb = b - PREPW_BLOCKS - W2PW_BLOCKS;
        if (tid < NB) hcnt[tid] = 0;
        __syncthreads();
        const int ET = E + N;
        const int per = (ET + HBLOCKS - 1) / HBLOCKS;
        const int lo = hb * per;
        const int hi = (lo + per < ET) ? (lo + per) : ET;
        const int st = edge_stride(ei);
        for (int i = lo + tid; i < hi; i += 256) {
            const int d = (i < E) ? ei[(size_t)st * (E + i)] : (i - E);
            atomicAdd(&hcnt[d >> BSHIFT], 1);
        }
        __syncthreads();
        if (tid < NB) hist[tid * HBLOCKS + hb] = hcnt[tid];
    }
}

// ---- K1: h1 = x @ W1 via MFMA; h1 written as FOUR 64-ch quarter planes
//      (each 2.56 MB -> L2-resident per XCD with blockIdx&3 steering in k_agg1).
__global__ __launch_bounds__(256) void k_gemm1_mfma(
    const float* __restrict__ x, const _Float16* __restrict__ w1sw,
    const float* __restrict__ a1s, const float* __restrict__ a1d,
    __half* __restrict__ qh1,
    float* __restrict__ as1, float* __restrict__ ad1)
{
    const int lane = threadIdx.x & 63;
    const int wid = (blockIdx.x * 256 + threadIdx.x) >> 6;
    const int m0 = wid * 16;
    const int g = lane >> 4, lm = lane & 15;
    const int arow = m0 + lm;
    half8 a[4];
    if (arow < N) {
        const float* xr = x + (size_t)arow * F;
#pragma unroll
        for (int ks = 0; ks < 4; ks++) {
            const float4 v0 = *reinterpret_cast<const float4*>(&xr[ks * 32 + g * 8]);
            const float4 v1 = *reinterpret_cast<const float4*>(&xr[ks * 32 + g * 8 + 4]);
            half8 t;
            t[0] = (_Float16)v0.x; t[1] = (_Float16)v0.y; t[2] = (_Float16)v0.z; t[3] = (_Float16)v0.w;
            t[4] = (_Float16)v1.x; t[5] = (_Float16)v1.y; t[6] = (_Float16)v1.z; t[7] = (_Float16)v1.w;
            a[ks] = t;
        }
    } else {
#pragma unroll
        for (int ks = 0; ks < 4; ks++) {
            half8 t;
#pragma unroll
            for (int j = 0; j < 8; j++) t[j] = (_Float16)0.f;
            a[ks] = t;
        }
    }
    const int rbase = m0 + g * 4;
    float ps[4] = {0.f, 0.f, 0.f, 0.f}, pd[4] = {0.f, 0.f, 0.f, 0.f};
#pragma unroll
    for (int nt = 0; nt < 16; nt++) {
        f32x4 acc = {0.f, 0.f, 0.f, 0.f};
#pragma unroll
        for (int ks = 0; ks < 4; ks++) {
            const half8 bfr = *reinterpret_cast<const half8*>(&w1sw[(size_t)((ks * 16 + nt) * 64 + lane) * 8]);
            acc = __builtin_amdgcn_mfma_f32_16x16x32_f16(a[ks], bfr, acc, 0, 0, 0);
        }
        const int col = nt * 16 + lm;
        const int q = col >> 6, cq = col & 63;
        const float av = a1s[col], dv = a1d[col];
#pragma unroll
        for (int r = 0; r < 4; r++) {
            const int row = rbase + r;
            if (row < N) qh1[(size_t)q * QS + (size_t)row * 64 + cq] = __float2half((float)acc[r]);
            ps[r] = fmaf((float)acc[r], av, ps[r]);
            pd[r] = fmaf((float)acc[r], dv, pd[r]);
        }
        if (nt & 1) {
#pragma unroll
            for (int off = 1; off <= 8; off <<= 1) {
#pragma unroll
                for (int r = 0; r < 4; r++) {
                    ps[r] += __shfl_xor(ps[r], off);
                    pd[r] += __shfl_xor(pd[r], off);
                }
            }
            if (lm == 0) {
                const int head = nt >> 1;
#pragma unroll
                for (int r = 0; r < 4; r++) {
                    const int row = rbase + r;
                    if (row < N) {
                        as1[row * HEADS + head] = ps[r];
                        ad1[row * HEADS + head] = pd[r];
                    }
                }
            }
#pragma unroll
            for (int r = 0; r < 4; r++) { ps[r] = 0.f; pd[r] = 0.f; }
        }
    }
}

// ---- K3: scatter with FUSED scan. Each block redundantly computes the full
//      2D exclusive scan of hist (L2-resident, ~160KB read) -> its own cursor
//      column; block 0 also writes bucket starts for k_bucket.
__global__ __launch_bounds__(256) void k_scatter2(
    const int* __restrict__ ei, int E, const int* __restrict__ hist,
    int* __restrict__ buck, int* __restrict__ bstart)
{
    __shared__ int cur[NB];
    __shared__ int bs[160];
    __shared__ int wbase[4];
    const int hb = blockIdx.x;
    const int tid = threadIdx.x;
    const int lane = tid & 63, wid = tid >> 6;
    int rp = 0;
    if (tid < NB) {
        const int4* hp = (const int4*)&hist[tid * HBLOCKS];
        int s = 0;
#pragma unroll 4
        for (int k = 0; k < 64; k++) {
            const int4 v = hp[k];
            s += (v.x + v.y) + (v.z + v.w);
            const int b4 = 4 * k;
            rp += ((b4 + 0) < hb ? v.x : 0) + ((b4 + 1) < hb ? v.y : 0)
                + ((b4 + 2) < hb ? v.z : 0) + ((b4 + 3) < hb ? v.w : 0);
        }
        bs[tid] = s;
    }
    __syncthreads();
    // exclusive scan of bs[0..NB)
    const int vin = (tid < NB) ? bs[tid] : 0;
    int v = vin;
#pragma unroll
    for (int off = 1; off < 64; off <<= 1) {
        const int u = __shfl_up(v, off, 64);
        if (lane >= off) v += u;
    }
    if (lane == 63) wbase[wid] = v;
    __syncthreads();
    if (tid < 64) {
        int w = (lane < 4) ? wbase[lane] : 0;
        const int orig = w;
#pragma unroll
        for (int off = 1; off < 4; off <<= 1) {
            const int u = __shfl_up(w, off, 64);
            if (lane >= off) w += u;
        }
        if (lane < 4) wbase[lane] = w - orig;
    }
    __syncthreads();
    if (tid < NB) {
        const int base = wbase[wid] + v - vin;   // exclusive global base of bucket tid
        cur[tid] = base + rp;
        if (hb == 0) bstart[tid] = base;
    }
    __syncthreads();
    const int ET = E + N;
    const int per = (ET + HBLOCKS - 1) / HBLOCKS;
    const int lo = hb * per;
    const int hi = (lo + per < ET) ? (lo + per) : ET;
    const int st = edge_stride(ei);
    for (int i = lo + tid; i < hi; i += 256) {
        int s, d;
        if (i < E) { s = ei[(size_t)st * i]; d = ei[(size_t)st * (E + i)]; }
        else       { s = i - E; d = i - E; }
        const int slot = atomicAdd(&cur[d >> BSHIFT], 1);
        buck[slot] = ((d & 127) << 16) | s;
    }
}

// ---- K4: per-bucket counting sort -> csr + rowptr (+ 64 zero sentinels past ET).
__global__ __launch_bounds__(256) void k_bucket(
    const int* __restrict__ bstart, const int* __restrict__ buck, int ET,
    int* __restrict__ csr, int* __restrict__ rowptr)
{
    __shared__ int cnt[128];
    __shared__ int pfx[128];
    const int b = blockIdx.x;
    const int tid = threadIdx.x;
    const int start = bstart[b];
    const int end = (b == NB - 1) ? ET : bstart[b + 1];
    if (tid < 128) cnt[tid] = 0;
    __syncthreads();
    for (int i = start + tid; i < end; i += 256)
        atomicAdd(&cnt[buck[i] >> 16], 1);
    __syncthreads();
    if (tid < 128) pfx[tid] = cnt[tid];
    __syncthreads();
    for (int off = 1; off < 128; off <<= 1) {
        int u = 0;
        if (tid < 128 && tid >= off) u = pfx[tid - off];
        __syncthreads();
        if (tid < 128) pfx[tid] += u;
        __syncthreads();
    }
    if (tid < 128) {
        const int node = b * 128 + tid;
        const int ebase = start + pfx[tid] - cnt[tid];
        if (node < N) rowptr[node] = ebase;
        cnt[tid] = ebase;
    }
    if (b == NB - 1 && tid == 0) rowptr[N] = ET;
    if (b == NB - 1 && tid < 64) csr[ET + tid] = 0;   // sentinels: safe 64-wide producer reads
    __syncthreads();
    for (int i = start + tid; i < end; i += 256) {
        const int val = buck[i];
        const int slot = atomicAdd(&cnt[val >> 16], 1);
        csr[slot] = val & 0xFFFF;
    }
}

// ---- K6: layer-1 aggregation on L2-resident quarter planes. Phase A stages
//      BOTH the 2 per-head weights AND the csr index into LDS (one edge/lane,
//      2 exps). Phase B reads int4/float4 from LDS (broadcast, ~60cy) and keeps
//      8 independent plane-gathers in flight -> shorter dependent chain + deep MLP.
__global__ __launch_bounds__(256) void k_agg1(
    const int* __restrict__ rowptr, const int* __restrict__ csr,
    const __half* __restrict__ qh1,
    const float* __restrict__ as1, const float* __restrict__ ad1,
    const float* __restrict__ b1, __half* __restrict__ h1p)
{
    __shared__ __align__(16) float wlds[8][2][36];
    __shared__ __align__(16) int slds[8][36];
    const int tid = threadIdx.x;
    const int l5 = tid & 31;                     // lane within node group
    const int sub = tid >> 5;                    // node slot 0..7
    const int hq = blockIdx.x & 3;               // quarter -> XCD steering
    const int n = (blockIdx.x >> 2) * 8 + sub;   // node
    const int cq = l5 * 2;                       // channel pair within quarter
    const int hsel = l5 >> 4;                    // consumer head-sub (0/1)
    const float2 dv2 = *reinterpret_cast<const float2*>(&ad1[n * HEADS + hq * 2]);
    const int beg = rowptr[n], end = rowptr[n + 1];
    const __half* plane = qh1 + (size_t)hq * QS;
    float* w0 = wlds[sub][0];
    float* w1 = wlds[sub][1];
    const float* wc = wlds[sub][hsel];
    int* sl = slds[sub];
    float ax = 0.f, ay = 0.f, accw = 0.f;
    for (int cs = beg; cs < end; cs += 32) {
        const int m = end - cs;
        // phase A: one edge per lane -> LDS {s, w_head0, w_head1}; zero-pad past m
        {
            const int s = csr[cs + l5];          // sentinel-safe
            const float2 a2 = *reinterpret_cast<const float2*>(&as1[s * HEADS + hq * 2]);
            const bool ok = l5 < m;
            sl[l5] = s;
            w0[l5] = ok ? __expf(lrelu(a2.x + dv2.x)) : 0.f;
            w1[l5] = ok ? __expf(lrelu(a2.y + dv2.y)) : 0.f;
        }
        // phase B: 8 edges in flight (LDS int4/float4 broadcast + 8 gathers)
        const int mm8 = (m < 32) ? ((m + 7) & ~7) : 32;
        for (int j0 = 0; j0 < mm8; j0 += 8) {
            const int4 sa = *reinterpret_cast<const int4*>(&sl[j0]);
            const int4 sb = *reinterpret_cast<const int4*>(&sl[j0 + 4]);
            const float4 wa = *reinterpret_cast<const float4*>(&wc[j0]);
            const float4 wb = *reinterpret_cast<const float4*>(&wc[j0 + 4]);
            const float2 gA = __half22float2(*reinterpret_cast<const __half2*>(&plane[(size_t)sa.x * 64 + cq]));
            const float2 gB = __half22float2(*reinterpret_cast<const __half2*>(&plane[(size_t)sa.y * 64 + cq]));
            const float2 gC = __half22float2(*reinterpret_cast<const __half2*>(&plane[(size_t)sa.z * 64 + cq]));
            const float2 gD = __half22float2(*reinterpret_cast<const __half2*>(&plane[(size_t)sa.w * 64 + cq]));
            const float2 gE = __half22float2(*reinterpret_cast<const __half2*>(&plane[(size_t)sb.x * 64 + cq]));
            const float2 gF = __half22float2(*reinterpret_cast<const __half2*>(&plane[(size_t)sb.y * 64 + cq]));
            const float2 gG = __half22float2(*reinterpret_cast<const __half2*>(&plane[(size_t)sb.z * 64 + cq]));
            const float2 gH = __half22float2(*reinterpret_cast<const __half2*>(&plane[(size_t)sb.w * 64 + cq]));
            accw += (wa.x + wa.y) + (wa.z + wa.w) + (wb.x + wb.y) + (wb.z + wb.w);
            ax = fmaf(wa.x, gA.x, ax); ay = fmaf(wa.x, gA.y, ay);
            ax = fmaf(wa.y, gB.x, ax); ay = fmaf(wa.y, gB.y, ay);
            ax = fmaf(wa.z, gC.x, ax); ay = fmaf(wa.z, gC.y, ay);
            ax = fmaf(wa.w, gD.x, ax); ay = fmaf(wa.w, gD.y, ay);
            ax = fmaf(wb.x, gE.x, ax); ay = fmaf(wb.x, gE.y, ay);
            ax = fmaf(wb.y, gF.x, ax); ay = fmaf(wb.y, gF.y, ay);
            ax = fmaf(wb.z, gG.x, ax); ay = fmaf(wb.z, gG.y, ay);
            ax = fmaf(wb.w, gH.x, ax); ay = fmaf(wb.w, gH.y, ay);
        }
    }
    const float inv = 1.f / accw;
    const int ch = hq * 64 + cq;
    float ox = ax * inv + b1[ch];
    float oy = ay * inv + b1[ch + 1];
    ox = (ox > 0.f) ? ox : (__expf(ox) - 1.f);
    oy = (oy > 0.f) ? oy : (__expf(oy) - 1.f);
    *reinterpret_cast<__half2*>(&h1p[(size_t)n * C1 + ch]) = __floats2half2_rn(ox, oy);
}

// ---- K7: h2 = h1p @ W2 via MFMA (NC=40 padded to 3x16 col tiles); fused as2/ad2.
//      h2h stored with row stride NCP=64 halves (128B = exactly one cache line).
__global__ __launch_bounds__(256) void k_gemm2_mfma(
    const __half* __restrict__ h1p, const _Float16* __restrict__ w2sw,
    const float* __restrict__ a2s, const float* __restrict__ a2d,
    __half* __restrict__ h2h, float* __restrict__ as2, float* __restrict__ ad2)
{
    const int lane = threadIdx.x & 63;
    const int wid = (blockIdx.x * 256 + threadIdx.x) >> 6;
    const int m0 = wid * 16;
    const int g = lane >> 4, lm = lane & 15;
    const int arow = m0 + lm;
    half8 a[8];
    if (arow < N) {
        const __half* hr = h1p + (size_t)arow * C1;
#pragma unroll
        for (int ks = 0; ks < 8; ks++)
            a[ks] = *reinterpret_cast<const half8*>(&hr[ks * 32 + g * 8]);
    } else {
#pragma unroll
        for (int ks = 0; ks < 8; ks++) {
            half8 t;
#pragma unroll
            for (int j = 0; j < 8; j++) t[j] = (_Float16)0.f;
            a[ks] = t;
        }
    }
    f32x4 acc[3];
#pragma unroll
    for (int nt = 0; nt < 3; nt++) acc[nt] = (f32x4){0.f, 0.f, 0.f, 0.f};
#pragma unroll
    for (int ks = 0; ks < 8; ks++) {
#pragma unroll
        for (int nt = 0; nt < 3; nt++) {
            const half8 bfr = *reinterpret_cast<const half8*>(&w2sw[(size_t)((ks * 3 + nt) * 64 + lane) * 8]);
            acc[nt] = __builtin_amdgcn_mfma_f32_16x16x32_f16(a[ks], bfr, acc[nt], 0, 0, 0);
        }
    }
    const int rbase = m0 + g * 4;
    float av[3], dvv[3];
#pragma unroll
    for (int nt = 0; nt < 3; nt++) {
        const int col = nt * 16 + lm;
        av[nt]  = (col < NC) ? a2s[col] : 0.f;
        dvv[nt] = (col < NC) ? a2d[col] : 0.f;
    }
#pragma unroll
    for (int r = 0; r < 4; r++) {
        const int row = rbase + r;
        float ps = 0.f, pd = 0.f;
#pragma unroll
        for (int nt = 0; nt < 3; nt++) {
            const float v = (float)acc[nt][r];
            const int col = nt * 16 + lm;
            if (row < N && col < NC) h2h[(size_t)row * NCP + col] = __float2half(v);
            ps = fmaf(v, av[nt], ps);
            pd = fmaf(v, dvv[nt], pd);
        }
#pragma unroll
        for (int off = 1; off <= 8; off <<= 1) {
            ps += __shfl_xor(ps, off);
            pd += __shfl_xor(pd, off);
        }
        if (lm == 0 && row < N) { as2[row] = ps; ad2[row] = pd; }
    }
}

// ---- K8: layer-2 aggregation + bias + log_softmax. One wave/node.
//      LDS stages {s, w} per 64-edge burst (one exp/lane); phase B 8 edges
//      in flight via LDS int4/float4 broadcast. h2h L2-resident (2.56 MB).
__global__ __launch_bounds__(256) void k_agg2(
    const int* __restrict__ rowptr, const int* __restrict__ csr,
    const __half* __restrict__ h2h, const float* __restrict__ as2,
    const float* __restrict__ ad2, const float* __restrict__ b2,
    float* __restrict__ out)
{
    __shared__ __align__(16) float wl[4][68];
    __shared__ __align__(16) int sl2[4][68];
    const int lane = threadIdx.x & 63;
    const int wv = threadIdx.x >> 6;
    const int n = (blockIdx.x * blockDim.x + threadIdx.x) >> 6;
    const int c = lane;
    const int cc = (c < NC) ? c : (NC - 1);
    const float adv = ad2[n];
    const int beg = rowptr[n], end = rowptr[n + 1];
    float* w = wl[wv];
    int* sl = sl2[wv];
    float acc = 0.f, accw = 0.f;
    for (int cs = beg; cs < end; cs += 64) {
        const int m = end - cs;
        // phase A: one edge per lane -> LDS {s, w}; zero-pad past m
        {
            const int s = csr[cs + lane];        // sentinel-safe (64 zeros past ET)
            sl[lane] = s;
            w[lane] = (lane < m) ? __expf(lrelu(as2[s] + adv)) : 0.f;
        }
        // phase B: 8 edges in flight
        const int mm8 = (m < 64) ? ((m + 7) & ~7) : 64;
        for (int j0 = 0; j0 < mm8; j0 += 8) {
            const int4 sa = *reinterpret_cast<const int4*>(&sl[j0]);
            const int4 sb = *reinterpret_cast<const int4*>(&sl[j0 + 4]);
            const float4 wa = *reinterpret_cast<const float4*>(&w[j0]);
            const float4 wb = *reinterpret_cast<const float4*>(&w[j0 + 4]);
            const float g0 = __half2float(h2h[(size_t)sa.x * NCP + cc]);
            const float g1 = __half2float(h2h[(size_t)sa.y * NCP + cc]);
            const float g2 = __half2float(h2h[(size_t)sa.z * NCP + cc]);
            const float g3 = __half2float(h2h[(size_t)sa.w * NCP + cc]);
            const float g4 = __half2float(h2h[(size_t)sb.x * NCP + cc]);
            const float g5 = __half2float(h2h[(size_t)sb.y * NCP + cc]);
            const float g6 = __half2float(h2h[(size_t)sb.z * NCP + cc]);
            const float g7 = __half2float(h2h[(size_t)sb.w * NCP + cc]);
            accw += (wa.x + wa.y) + (wa.z + wa.w) + (wb.x + wb.y) + (wb.z + wb.w);
            acc = fmaf(wa.x, g0, acc);
            acc = fmaf(wa.y, g1, acc);
            acc = fmaf(wa.z, g2, acc);
            acc = fmaf(wa.w, g3, acc);
            acc = fmaf(wb.x, g4, acc);
            acc = fmaf(wb.y, g5, acc);
            acc = fmaf(wb.z, g6, acc);
            acc = fmaf(wb.w, g7, acc);
        }
    }
    const float v = acc / accw + b2[cc];
    float m = (c < NC) ? v : -1e30f;
#pragma unroll
    for (int off = 32; off >= 1; off >>= 1) m = fmaxf(m, __shfl_xor(m, off));
    float S = (c < NC) ? __expf(v - m) : 0.f;
#pragma unroll
    for (int off = 32; off >= 1; off >>= 1) S += __shfl_xor(S, off);
    if (c < NC) out[(size_t)n * NC + c] = v - m - logf(S);
}

extern "C" void kernel_launch(void* const* d_in, const int* in_sizes, int n_in,
                              void* d_out, int out_size, void* d_ws, size_t ws_size,
                              hipStream_t stream)
{
    const float* x   = (const float*)d_in[0];
    const int*   ei  = (const int*)d_in[1];
    const float* W1  = (const float*)d_in[2];
    const float* a1s = (const float*)d_in[3];
    const float* a1d = (const float*)d_in[4];
    const float* b1  = (const float*)d_in[5];
    const float* W2  = (const float*)d_in[6];
    const float* a2s = (const float*)d_in[7];
    const float* a2d = (const float*)d_in[8];
    const float* b2  = (const float*)d_in[9];
    float* out = (float*)d_out;

    const int E  = in_sizes[1] / 2;
    const int ET = E + N;

    auto align64 = [](size_t v) { return (v + 63) & ~(size_t)63; };
    char* ws = (char*)d_ws;
    size_t off = 0;
    _Float16* w1sw = (_Float16*)(ws + off); off = align64(off + (size_t)4096 * 8 * 2);
    _Float16* w2sw = (_Float16*)(ws + off); off = align64(off + (size_t)1536 * 8 * 2);
    __half* qh1 = (__half*)(ws + off); off = align64(off + (size_t)N * C1 * 2);   // 4 quarter planes
    __half* h1p = (__half*)(ws + off); off = align64(off + (size_t)N * C1 * 2);
    __half* h2h = (__half*)(ws + off); off = align64(off + (size_t)N * NCP * 2);
    float* as1 = (float*)(ws + off); off = align64(off + (size_t)N * HEADS * 4);
    float* ad1 = (float*)(ws + off); off = align64(off + (size_t)N * HEADS * 4);
    float* as2 = (float*)(ws + off); off = align64(off + (size_t)N * 4);
    float* ad2 = (float*)(ws + off); off = align64(off + (size_t)N * 4);
    int* hist   = (int*)(ws + off); off = align64(off + (size_t)HM * 4);
    int* bstart = (int*)(ws + off); off = align64(off + (size_t)NB * 4);
    int* buck   = (int*)(ws + off); off = align64(off + (size_t)ET * 4);
    int* rowptr = (int*)(ws + off); off = align64(off + (size_t)(N + 1) * 4);
    int* csr    = (int*)(ws + off); off = align64(off + (size_t)ET * 4 + 256);

    k_misc<<<PREPW_BLOCKS + W2PW_BLOCKS + HBLOCKS, 256, 0, stream>>>(W1, w1sw, W2, w2sw, ei, E, hist);
    k_gemm1_mfma<<<313, 256, 0, stream>>>(x, w1sw, a1s, a1d, qh1, as1, ad1);
    k_scatter2<<<HBLOCKS, 256, 0, stream>>>(ei, E, hist, buck, bstart);
    k_bucket<<<NB, 256, 0, stream>>>(bstart, buck, ET, csr, rowptr);
    k_agg1<<<N / 2, 256, 0, stream>>>(rowptr, csr, qh1, as1, ad1, b1, h1p);
    k_gemm2_mfma<<<313, 256, 0, stream>>>(h1p, w2sw, a2s, a2d, h2h, as2, ad2);
    k_agg2<<<5000, 256, 0, stream>>>(rowptr, csr, h2h, as2, ad2, b2, out);
}

// Round 10
// 182.861 us; speedup vs baseline: 1.4480x; 1.0028x over previous
//
#include <hip/hip_runtime.h>
#include <hip/hip_fp16.h>
#include <math.h>

#define N 20000
#define F 128
#define C1 256   // HEADS*HIDDEN
#define HEADS 8
#define HID 32
#define NC 40
#define NCP 64   // padded h2h row stride (1 cache line)
#define NEG 0.2f

#define BSHIFT 7
#define NB 157        // buckets of 128 nodes
#define HBLOCKS 256
#define HM (NB * HBLOCKS)

#define PREPW_BLOCKS 16
#define W2PW_BLOCKS 6   // 24 frags * 64 lanes = 1536 half8 slots

#define QS ((size_t)N * 64)   // quarter-plane element stride
#define AGG1_BLOCKS 2048

typedef _Float16 half8 __attribute__((ext_vector_type(8)));
typedef float f32x4 __attribute__((ext_vector_type(4)));

__device__ __forceinline__ int edge_stride(const int* ei) {
    return (ei[1] == 0 && ei[3] == 0 && ei[5] == 0 && ei[7] == 0 && ei[9] == 0) ? 2 : 1;
}

__device__ __forceinline__ float lrelu(float v) { return v > 0.f ? v : NEG * v; }

// ---- K0: fused prep (W1 swizzle + W2 swizzle) + bucket histogram (LDS atomics only)
__global__ __launch_bounds__(256) void k_misc(
    const float* __restrict__ W1, _Float16* __restrict__ w1sw,
    const float* __restrict__ W2, _Float16* __restrict__ w2sw,
    const int* __restrict__ ei, int E, int* __restrict__ hist)
{
    const int b = blockIdx.x;
    const int tid = threadIdx.x;
    if (b < PREPW_BLOCKS) {
        const int slot = b * 256 + tid;
        const int lane = slot & 63;
        const int tile = slot >> 6;
        const int nt = tile & 15, ks = tile >> 4;
        const int n = nt * 16 + (lane & 15);
        const int k0 = ks * 32 + (lane >> 4) * 8;
        half8 tmp;
#pragma unroll
        for (int j = 0; j < 8; j++) tmp[j] = (_Float16)W1[(k0 + j) * C1 + n];
        *reinterpret_cast<half8*>(&w1sw[(size_t)slot * 8]) = tmp;
    } else if (b < PREPW_BLOCKS + W2PW_BLOCKS) {
        const int slot = (b - PREPW_BLOCKS) * 256 + tid;   // 0..1535
        const int lane = slot & 63;
        const int f = slot >> 6;          // 0..23
        const int nt = f % 3, ks = f / 3;
        const int n = nt * 16 + (lane & 15);
        const int k0 = ks * 32 + (lane >> 4) * 8;
        half8 tmp;
#pragma unroll
        for (int j = 0; j < 8; j++)
            tmp[j] = (n < NC) ? (_Float16)W2[(k0 + j) * NC + n] : (_Float16)0.f;
        *reinterpret_cast<half8*>(&w2sw[(size_t)slot * 8]) = tmp;
    } else {
        __shared__ int hcnt[NB];
        const int hb = b - PREPW_BLOCKS - W2PW_BLOCKS;
        if (tid < NB) hcnt[tid] = 0;
        __syncthreads();
        const int ET = E + N;
        const int per = (ET + HBLOCKS - 1) / HBLOCKS;
        const int lo = hb * per;
        const int hi = (lo + per < ET) ? (lo + per) : ET;
        const int st = edge_stride(ei);
        for (int i = lo + tid; i < hi; i += 256) {
            const int d = (i < E) ? ei[(size_t)st * (E + i)] : (i - E);
            atomicAdd(&hcnt[d >> BSHIFT], 1);
        }
        __syncthreads();
        if (tid < NB) hist[tid * HBLOCKS + hb] = hcnt[tid];
    }
}

// ---- K1: h1 = x @ W1 via MFMA -> FOUR 64-ch quarter planes. Two waves per
//      16-row tile (wave handles 8 of 16 col-tiles) -> 2504 waves = 2.4/SIMD
//      (was 1.2: latency-serial). Head projections split cleanly: hs=0 computes
//      heads 0-3, hs=1 heads 4-7.
__global__ __launch_bounds__(256) void k_gemm1_mfma(
    const float* __restrict__ x, const _Float16* __restrict__ w1sw,
    const float* __restrict__ a1s, const float* __restrict__ a1d,
    __half* __restrict__ qh1,
    float* __restrict__ as1, float* __restrict__ ad1)
{
    const int lane = threadIdx.x & 63;
    const int wid = (blockIdx.x * 256 + threadIdx.x) >> 6;   // 0..2503
    const int tile = wid >> 1;
    const int hs = wid & 1;                                  // col half
    const int m0 = tile * 16;
    const int g = lane >> 4, lm = lane & 15;
    const int arow = m0 + lm;
    half8 a[4];
    if (arow < N) {
        const float* xr = x + (size_t)arow * F;
#pragma unroll
        for (int ks = 0; ks < 4; ks++) {
            const float4 v0 = *reinterpret_cast<const float4*>(&xr[ks * 32 + g * 8]);
            const float4 v1 = *reinterpret_cast<const float4*>(&xr[ks * 32 + g * 8 + 4]);
            half8 t;
            t[0] = (_Float16)v0.x; t[1] = (_Float16)v0.y; t[2] = (_Float16)v0.z; t[3] = (_Float16)v0.w;
            t[4] = (_Float16)v1.x; t[5] = (_Float16)v1.y; t[6] = (_Float16)v1.z; t[7] = (_Float16)v1.w;
            a[ks] = t;
        }
    } else {
#pragma unroll
        for (int ks = 0; ks < 4; ks++) {
            half8 t;
#pragma unroll
            for (int j = 0; j < 8; j++) t[j] = (_Float16)0.f;
            a[ks] = t;
        }
    }
    const int rbase = m0 + g * 4;
    float ps[4] = {0.f, 0.f, 0.f, 0.f}, pd[4] = {0.f, 0.f, 0.f, 0.f};
#pragma unroll
    for (int ntl = 0; ntl < 8; ntl++) {
        const int nt = hs * 8 + ntl;
        f32x4 acc = {0.f, 0.f, 0.f, 0.f};
#pragma unroll
        for (int ks = 0; ks < 4; ks++) {
            const half8 bfr = *reinterpret_cast<const half8*>(&w1sw[(size_t)((ks * 16 + nt) * 64 + lane) * 8]);
            acc = __builtin_amdgcn_mfma_f32_16x16x32_f16(a[ks], bfr, acc, 0, 0, 0);
        }
        const int col = nt * 16 + lm;
        const int q = col >> 6, cq = col & 63;
        const float av = a1s[col], dv = a1d[col];
#pragma unroll
        for (int r = 0; r < 4; r++) {
            const int row = rbase + r;
            if (row < N) qh1[(size_t)q * QS + (size_t)row * 64 + cq] = __float2half((float)acc[r]);
            ps[r] = fmaf((float)acc[r], av, ps[r]);
            pd[r] = fmaf((float)acc[r], dv, pd[r]);
        }
        if (ntl & 1) {
#pragma unroll
            for (int off = 1; off <= 8; off <<= 1) {
#pragma unroll
                for (int r = 0; r < 4; r++) {
                    ps[r] += __shfl_xor(ps[r], off);
                    pd[r] += __shfl_xor(pd[r], off);
                }
            }
            if (lm == 0) {
                const int head = hs * 4 + (ntl >> 1);
#pragma unroll
                for (int r = 0; r < 4; r++) {
                    const int row = rbase + r;
                    if (row < N) {
                        as1[row * HEADS + head] = ps[r];
                        ad1[row * HEADS + head] = pd[r];
                    }
                }
            }
#pragma unroll
            for (int r = 0; r < 4; r++) { ps[r] = 0.f; pd[r] = 0.f; }
        }
    }
}

// ---- K3: scatter with FUSED scan. Each block redundantly computes the full
//      2D exclusive scan of hist (L2-resident, ~160KB read) -> its own cursor
//      column; block 0 also writes bucket starts for k_bucket.
__global__ __launch_bounds__(256) void k_scatter2(
    const int* __restrict__ ei, int E, const int* __restrict__ hist,
    int* __restrict__ buck, int* __restrict__ bstart)
{
    __shared__ int cur[NB];
    __shared__ int bs[160];
    __shared__ int wbase[4];
    const int hb = blockIdx.x;
    const int tid = threadIdx.x;
    const int lane = tid & 63, wid = tid >> 6;
    int rp = 0;
    if (tid < NB) {
        const int4* hp = (const int4*)&hist[tid * HBLOCKS];
        int s = 0;
#pragma unroll 4
        for (int k = 0; k < 64; k++) {
            const int4 v = hp[k];
            s += (v.x + v.y) + (v.z + v.w);
            const int b4 = 4 * k;
            rp += ((b4 + 0) < hb ? v.x : 0) + ((b4 + 1) < hb ? v.y : 0)
                + ((b4 + 2) < hb ? v.z : 0) + ((b4 + 3) < hb ? v.w : 0);
        }
        bs[tid] = s;
    }
    __syncthreads();
    // exclusive scan of bs[0..NB)
    const int vin = (tid < NB) ? bs[tid] : 0;
    int v = vin;
#pragma unroll
    for (int off = 1; off < 64; off <<= 1) {
        const int u = __shfl_up(v, off, 64);
        if (lane >= off) v += u;
    }
    if (lane == 63) wbase[wid] = v;
    __syncthreads();
    if (tid < 64) {
        int w = (lane < 4) ? wbase[lane] : 0;
        const int orig = w;
#pragma unroll
        for (int off = 1; off < 4; off <<= 1) {
            const int u = __shfl_up(w, off, 64);
            if (lane >= off) w += u;
        }
        if (lane < 4) wbase[lane] = w - orig;
    }
    __syncthreads();
    if (tid < NB) {
        const int base = wbase[wid] + v - vin;   // exclusive global base of bucket tid
        cur[tid] = base + rp;
        if (hb == 0) bstart[tid] = base;
    }
    __syncthreads();
    const int ET = E + N;
    const int per = (ET + HBLOCKS - 1) / HBLOCKS;
    const int lo = hb * per;
    const int hi = (lo + per < ET) ? (lo + per) : ET;
    const int st = edge_stride(ei);
    for (int i = lo + tid; i < hi; i += 256) {
        int s, d;
        if (i < E) { s = ei[(size_t)st * i]; d = ei[(size_t)st * (E + i)]; }
        else       { s = i - E; d = i - E; }
        const int slot = atomicAdd(&cur[d >> BSHIFT], 1);
        buck[slot] = ((d & 127) << 16) | s;
    }
}

// ---- K4: per-bucket counting sort -> csr + rowptr (+ 64 zero sentinels past ET).
__global__ __launch_bounds__(256) void k_bucket(
    const int* __restrict__ bstart, const int* __restrict__ buck, int ET,
    int* __restrict__ csr, int* __restrict__ rowptr)
{
    __shared__ int cnt[128];
    __shared__ int pfx[128];
    const int b = blockIdx.x;
    const int tid = threadIdx.x;
    const int start = bstart[b];
    const int end = (b == NB - 1) ? ET : bstart[b + 1];
    if (tid < 128) cnt[tid] = 0;
    __syncthreads();
    for (int i = start + tid; i < end; i += 256)
        atomicAdd(&cnt[buck[i] >> 16], 1);
    __syncthreads();
    if (tid < 128) pfx[tid] = cnt[tid];
    __syncthreads();
    for (int off = 1; off < 128; off <<= 1) {
        int u = 0;
        if (tid < 128 && tid >= off) u = pfx[tid - off];
        __syncthreads();
        if (tid < 128) pfx[tid] += u;
        __syncthreads();
    }
    if (tid < 128) {
        const int node = b * 128 + tid;
        const int ebase = start + pfx[tid] - cnt[tid];
        if (node < N) rowptr[node] = ebase;
        cnt[tid] = ebase;
    }
    if (b == NB - 1 && tid == 0) rowptr[N] = ET;
    if (b == NB - 1 && tid < 64) csr[ET + tid] = 0;   // sentinels: safe 64-wide producer reads
    __syncthreads();
    for (int i = start + tid; i < end; i += 256) {
        const int val = buck[i];
        const int slot = atomicAdd(&cnt[val >> 16], 1);
        csr[slot] = val & 0xFFFF;
    }
}

// ---- K6: layer-1 aggregation on L2-resident quarter planes. Grid-stride over
//      nodes (balances Poisson degree variance; 5x fewer blocks to dispatch).
//      Phase A stages {s, w_head0, w_head1} into LDS (one edge/lane, 2 exps),
//      with next-burst csr/as1 PREFETCHED so the exp chain overlaps phase B.
//      Phase B: LDS int4/float4 broadcast + 8 independent plane-gathers in flight.
__global__ __launch_bounds__(256) void k_agg1(
    const int* __restrict__ rowptr, const int* __restrict__ csr,
    const __half* __restrict__ qh1,
    const float* __restrict__ as1, const float* __restrict__ ad1,
    const float* __restrict__ b1, __half* __restrict__ h1p)
{
    __shared__ __align__(16) float wlds[8][2][36];
    __shared__ __align__(16) int slds[8][36];
    const int tid = threadIdx.x;
    const int l5 = tid & 31;                     // lane within node group
    const int sub = tid >> 5;                    // node slot 0..7
    const int hq = blockIdx.x & 3;               // quarter -> XCD steering
    const int slotsPerQ = (gridDim.x >> 2) * 8;
    const int slot0 = (blockIdx.x >> 2) * 8 + sub;
    const int cq = l5 * 2;                       // channel pair within quarter
    const int hsel = l5 >> 4;                    // consumer head-sub (0/1)
    const __half* plane = qh1 + (size_t)hq * QS;
    float* w0 = wlds[sub][0];
    float* w1 = wlds[sub][1];
    const float* wc = wlds[sub][hsel];
    int* sl = slds[sub];
    const int ch = hq * 64 + cq;
    const float bx = b1[ch], by = b1[ch + 1];
    for (int n = slot0; n < N; n += slotsPerQ) {
        const float2 dv2 = *reinterpret_cast<const float2*>(&ad1[n * HEADS + hq * 2]);
        const int beg = rowptr[n], end = rowptr[n + 1];
        float ax = 0.f, ay = 0.f, accw = 0.f;
        // prefetch first burst's producer inputs (sentinel-safe)
        int s_pf = csr[beg + l5];
        float2 a_pf = *reinterpret_cast<const float2*>(&as1[s_pf * HEADS + hq * 2]);
        for (int cs = beg; cs < end; cs += 32) {
            const int m = end - cs;
            // phase A: write staged {s, w0, w1} from prefetched inputs
            {
                const bool ok = l5 < m;
                sl[l5] = s_pf;
                w0[l5] = ok ? __expf(lrelu(a_pf.x + dv2.x)) : 0.f;
                w1[l5] = ok ? __expf(lrelu(a_pf.y + dv2.y)) : 0.f;
            }
            // prefetch next burst (overlaps phase B)
            if (cs + 32 < end) {
                s_pf = csr[cs + 32 + l5];                       // sentinel-safe
                a_pf = *reinterpret_cast<const float2*>(&as1[s_pf * HEADS + hq * 2]);
            }
            // phase B: 8 edges in flight (LDS int4/float4 broadcast + 8 gathers)
            const int mm8 = (m < 32) ? ((m + 7) & ~7) : 32;
            for (int j0 = 0; j0 < mm8; j0 += 8) {
                const int4 sa = *reinterpret_cast<const int4*>(&sl[j0]);
                const int4 sb = *reinterpret_cast<const int4*>(&sl[j0 + 4]);
                const float4 wa = *reinterpret_cast<const float4*>(&wc[j0]);
                const float4 wb = *reinterpret_cast<const float4*>(&wc[j0 + 4]);
                const float2 gA = __half22float2(*reinterpret_cast<const __half2*>(&plane[(size_t)sa.x * 64 + cq]));
                const float2 gB = __half22float2(*reinterpret_cast<const __half2*>(&plane[(size_t)sa.y * 64 + cq]));
                const float2 gC = __half22float2(*reinterpret_cast<const __half2*>(&plane[(size_t)sa.z * 64 + cq]));
                const float2 gD = __half22float2(*reinterpret_cast<const __half2*>(&plane[(size_t)sa.w * 64 + cq]));
                const float2 gE = __half22float2(*reinterpret_cast<const __half2*>(&plane[(size_t)sb.x * 64 + cq]));
                const float2 gF = __half22float2(*reinterpret_cast<const __half2*>(&plane[(size_t)sb.y * 64 + cq]));
                const float2 gG = __half22float2(*reinterpret_cast<const __half2*>(&plane[(size_t)sb.z * 64 + cq]));
                const float2 gH = __half22float2(*reinterpret_cast<const __half2*>(&plane[(size_t)sb.w * 64 + cq]));
                accw += (wa.x + wa.y) + (wa.z + wa.w) + (wb.x + wb.y) + (wb.z + wb.w);
                ax = fmaf(wa.x, gA.x, ax); ay = fmaf(wa.x, gA.y, ay);
                ax = fmaf(wa.y, gB.x, ax); ay = fmaf(wa.y, gB.y, ay);
                ax = fmaf(wa.z, gC.x, ax); ay = fmaf(wa.z, gC.y, ay);
                ax = fmaf(wa.w, gD.x, ax); ay = fmaf(wa.w, gD.y, ay);
                ax = fmaf(wb.x, gE.x, ax); ay = fmaf(wb.x, gE.y, ay);
                ax = fmaf(wb.y, gF.x, ax); ay = fmaf(wb.y, gF.y, ay);
                ax = fmaf(wb.z, gG.x, ax); ay = fmaf(wb.z, gG.y, ay);
                ax = fmaf(wb.w, gH.x, ax); ay = fmaf(wb.w, gH.y, ay);
            }
        }
        const float inv = 1.f / accw;
        float ox = ax * inv + bx;
        float oy = ay * inv + by;
        ox = (ox > 0.f) ? ox : (__expf(ox) - 1.f);
        oy = (oy > 0.f) ? oy : (__expf(oy) - 1.f);
        *reinterpret_cast<__half2*>(&h1p[(size_t)n * C1 + ch]) = __floats2half2_rn(ox, oy);
    }
}

// ---- K7: h2 = h1p @ W2 via MFMA (NC=40 padded to 3x16 col tiles); fused as2/ad2.
//      h2h stored with row stride NCP=64 halves (128B = exactly one cache line).
__global__ __launch_bounds__(256) void k_gemm2_mfma(
    const __half* __restrict__ h1p, const _Float16* __restrict__ w2sw,
    const float* __restrict__ a2s, const float* __restrict__ a2d,
    __half* __restrict__ h2h, float* __restrict__ as2, float* __restrict__ ad2)
{
    const int lane = threadIdx.x & 63;
    const int wid = (blockIdx.x * 256 + threadIdx.x) >> 6;
    const int m0 = wid * 16;
    const int g = lane >> 4, lm = lane & 15;
    const int arow = m0 + lm;
    half8 a[8];
    if (arow < N) {
        const __half* hr = h1p + (size_t)arow * C1;
#pragma unroll
        for (int ks = 0; ks < 8; ks++)
            a[ks] = *reinterpret_cast<const half8*>(&hr[ks * 32 + g * 8]);
    } else {
#pragma unroll
        for (int ks = 0; ks < 8; ks++) {
            half8 t;
#pragma unroll
            for (int j = 0; j < 8; j++) t[j] = (_Float16)0.f;
            a[ks] = t;
        }
    }
    f32x4 acc[3];
#pragma unroll
    for (int nt = 0; nt < 3; nt++) acc[nt] = (f32x4){0.f, 0.f, 0.f, 0.f};
#pragma unroll
    for (int ks = 0; ks < 8; ks++) {
#pragma unroll
        for (int nt = 0; nt < 3; nt++) {
            const half8 bfr = *reinterpret_cast<const half8*>(&w2sw[(size_t)((ks * 3 + nt) * 64 + lane) * 8]);
            acc[nt] = __builtin_amdgcn_mfma_f32_16x16x32_f16(a[ks], bfr, acc[nt], 0, 0, 0);
        }
    }
    const int rbase = m0 + g * 4;
    float av[3], dvv[3];
#pragma unroll
    for (int nt = 0; nt < 3; nt++) {
        const int col = nt * 16 + lm;
        av[nt]  = (col < NC) ? a2s[col] : 0.f;
        dvv[nt] = (col < NC) ? a2d[col] : 0.f;
    }
#pragma unroll
    for (int r = 0; r < 4; r++) {
        const int row = rbase + r;
        float ps = 0.f, pd = 0.f;
#pragma unroll
        for (int nt = 0; nt < 3; nt++) {
            const float v = (float)acc[nt][r];
            const int col = nt * 16 + lm;
            if (row < N && col < NC) h2h[(size_t)row * NCP + col] = __float2half(v);
            ps = fmaf(v, av[nt], ps);
            pd = fmaf(v, dvv[nt], pd);
        }
#pragma unroll
        for (int off = 1; off <= 8; off <<= 1) {
            ps += __shfl_xor(ps, off);
            pd += __shfl_xor(pd, off);
        }
        if (lm == 0 && row < N) { as2[row] = ps; ad2[row] = pd; }
    }
}

// ---- K8: layer-2 aggregation + bias + log_softmax. One wave/node.
//      LDS stages {s, w} per 64-edge burst (one exp/lane, inputs PREFETCHED);
//      phase B 8 edges in flight. h2h L2-resident (2.56 MB).
__global__ __launch_bounds__(256) void k_agg2(
    const int* __restrict__ rowptr, const int* __restrict__ csr,
    const __half* __restrict__ h2h, const float* __restrict__ as2,
    const float* __restrict__ ad2, const float* __restrict__ b2,
    float* __restrict__ out)
{
    __shared__ __align__(16) float wl[4][68];
    __shared__ __align__(16) int sl2[4][68];
    const int lane = threadIdx.x & 63;
    const int wv = threadIdx.x >> 6;
    const int n = (blockIdx.x * blockDim.x + threadIdx.x) >> 6;
    const int c = lane;
    const int cc = (c < NC) ? c : (NC - 1);
    const float adv = ad2[n];
    const int beg = rowptr[n], end = rowptr[n + 1];
    float* w = wl[wv];
    int* sl = sl2[wv];
    float acc = 0.f, accw = 0.f;
    // prefetch first burst's producer inputs (sentinel-safe)
    int s_pf = csr[beg + lane];
    float a_pf = as2[s_pf];
    for (int cs = beg; cs < end; cs += 64) {
        const int m = end - cs;
        // phase A: staged {s, w} from prefetched inputs
        {
            sl[lane] = s_pf;
            w[lane] = (lane < m) ? __expf(lrelu(a_pf + adv)) : 0.f;
        }
        if (cs + 64 < end) {
            s_pf = csr[cs + 64 + lane];        // sentinel-safe
            a_pf = as2[s_pf];
        }
        // phase B: 8 edges in flight
        const int mm8 = (m < 64) ? ((m + 7) & ~7) : 64;
        for (int j0 = 0; j0 < mm8; j0 += 8) {
            const int4 sa = *reinterpret_cast<const int4*>(&sl[j0]);
            const int4 sb = *reinterpret_cast<const int4*>(&sl[j0 + 4]);
            const float4 wa = *reinterpret_cast<const float4*>(&w[j0]);
            const float4 wb = *reinterpret_cast<const float4*>(&w[j0 + 4]);
            const float g0 = __half2float(h2h[(size_t)sa.x * NCP + cc]);
            const float g1 = __half2float(h2h[(size_t)sa.y * NCP + cc]);
            const float g2 = __half2float(h2h[(size_t)sa.z * NCP + cc]);
            const float g3 = __half2float(h2h[(size_t)sa.w * NCP + cc]);
            const float g4 = __half2float(h2h[(size_t)sb.x * NCP + cc]);
            const float g5 = __half2float(h2h[(size_t)sb.y * NCP + cc]);
            const float g6 = __half2float(h2h[(size_t)sb.z * NCP + cc]);
            const float g7 = __half2float(h2h[(size_t)sb.w * NCP + cc]);
            accw += (wa.x + wa.y) + (wa.z + wa.w) + (wb.x + wb.y) + (wb.z + wb.w);
            acc = fmaf(wa.x, g0, acc);
            acc = fmaf(wa.y, g1, acc);
            acc = fmaf(wa.z, g2, acc);
            acc = fmaf(wa.w, g3, acc);
            acc = fmaf(wb.x, g4, acc);
            acc = fmaf(wb.y, g5, acc);
            acc = fmaf(wb.z, g6, acc);
            acc = fmaf(wb.w, g7, acc);
        }
    }
    const float v = acc / accw + b2[cc];
    float m = (c < NC) ? v : -1e30f;
#pragma unroll
    for (int off = 32; off >= 1; off >>= 1) m = fmaxf(m, __shfl_xor(m, off));
    float S = (c < NC) ? __expf(v - m) : 0.f;
#pragma unroll
    for (int off = 32; off >= 1; off >>= 1) S += __shfl_xor(S, off);
    if (c < NC) out[(size_t)n * NC + c] = v - m - logf(S);
}

extern "C" void kernel_launch(void* const* d_in, const int* in_sizes, int n_in,
                              void* d_out, int out_size, void* d_ws, size_t ws_size,
                              hipStream_t stream)
{
    const float* x   = (const float*)d_in[0];
    const int*   ei  = (const int*)d_in[1];
    const float* W1  = (const float*)d_in[2];
    const float* a1s = (const float*)d_in[3];
    const float* a1d = (const float*)d_in[4];
    const float* b1  = (const float*)d_in[5];
    const float* W2  = (const float*)d_in[6];
    const float* a2s = (const float*)d_in[7];
    const float* a2d = (const float*)d_in[8];
    const float* b2  = (const float*)d_in[9];
    float* out = (float*)d_out;

    const int E  = in_sizes[1] / 2;
    const int ET = E + N;

    auto align64 = [](size_t v) { return (v + 63) & ~(size_t)63; };
    char* ws = (char*)d_ws;
    size_t off = 0;
    _Float16* w1sw = (_Float16*)(ws + off); off = align64(off + (size_t)4096 * 8 * 2);
    _Float16* w2sw = (_Float16*)(ws + off); off = align64(off + (size_t)1536 * 8 * 2);
    __half* qh1 = (__half*)(ws + off); off = align64(off + (size_t)N * C1 * 2);   // 4 quarter planes
    __half* h1p = (__half*)(ws + off); off = align64(off + (size_t)N * C1 * 2);
    __half* h2h = (__half*)(ws + off); off = align64(off + (size_t)N * NCP * 2);
    float* as1 = (float*)(ws + off); off = align64(off + (size_t)N * HEADS * 4);
    float* ad1 = (float*)(ws + off); off = align64(off + (size_t)N * HEADS * 4);
    float* as2 = (float*)(ws + off); off = align64(off + (size_t)N * 4);
    float* ad2 = (float*)(ws + off); off = align64(off + (size_t)N * 4);
    int* hist   = (int*)(ws + off); off = align64(off + (size_t)HM * 4);
    int* bstart = (int*)(ws + off); off = align64(off + (size_t)NB * 4);
    int* buck   = (int*)(ws + off); off = align64(off + (size_t)ET * 4);
    int* rowptr = (int*)(ws + off); off = align64(off + (size_t)(N + 1) * 4);
    int* csr    = (int*)(ws + off); off = align64(off + (size_t)ET * 4 + 256);

    k_misc<<<PREPW_BLOCKS + W2PW_BLOCKS + HBLOCKS, 256, 0, stream>>>(W1, w1sw, W2, w2sw, ei, E, hist);
    k_gemm1_mfma<<<626, 256, 0, stream>>>(x, w1sw, a1s, a1d, qh1, as1, ad1);
    k_scatter2<<<HBLOCKS, 256, 0, stream>>>(ei, E, hist, buck, bstart);
    k_bucket<<<NB, 256, 0, stream>>>(bstart, buck, ET, csr, rowptr);
    k_agg1<<<AGG1_BLOCKS, 256, 0, stream>>>(rowptr, csr, qh1, as1, ad1, b1, h1p);
    k_gemm2_mfma<<<313, 256, 0, stream>>>(h1p, w2sw, a2s, a2d, h2h, as2, ad2);
    k_agg2<<<5000, 256, 0, stream>>>(rowptr, csr, h2h, as2, ad2, b2, out);
}

// Round 12
// 165.996 us; speedup vs baseline: 1.5951x; 1.1016x over previous
//
#include <hip/hip_runtime.h>
#include <hip/hip_fp16.h>
#include <math.h>

#define N 20000
#define F 128
#define C1 256   // HEADS*HIDDEN
#define HEADS 8
#define HID 32
#define NC 40
#define NCP 64   // padded h2h row stride (1 cache line)
#define NEG 0.2f

#define BSHIFT 7
#define NB 157        // buckets of 128 nodes
#define HBLOCKS 256
#define HM (NB * HBLOCKS)

#define PREPW_BLOCKS 16
#define W2PW_BLOCKS 6   // 24 frags * 64 lanes = 1536 half8 slots

#define QS ((size_t)N * 64)   // quarter-plane element stride
#define G1_BLOCKS 626         // gemm1 blocks (2504 waves, 2 waves/16-row tile)

typedef _Float16 half8 __attribute__((ext_vector_type(8)));
typedef float f32x4 __attribute__((ext_vector_type(4)));

__device__ __forceinline__ int edge_stride(const int* ei) {
    return (ei[1] == 0 && ei[3] == 0 && ei[5] == 0 && ei[7] == 0 && ei[9] == 0) ? 2 : 1;
}

__device__ __forceinline__ float lrelu(float v) { return v > 0.f ? v : NEG * v; }

// ---- K0: fused prep (W1 swizzle + W2 swizzle) + bucket histogram (LDS atomics only)
__global__ __launch_bounds__(256) void k_misc(
    const float* __restrict__ W1, _Float16* __restrict__ w1sw,
    const float* __restrict__ W2, _Float16* __restrict__ w2sw,
    const int* __restrict__ ei, int E, int* __restrict__ hist)
{
    const int b = blockIdx.x;
    const int tid = threadIdx.x;
    if (b < PREPW_BLOCKS) {
        const int slot = b * 256 + tid;
        const int lane = slot & 63;
        const int tile = slot >> 6;
        const int nt = tile & 15, ks = tile >> 4;
        const int n = nt * 16 + (lane & 15);
        const int k0 = ks * 32 + (lane >> 4) * 8;
        half8 tmp;
#pragma unroll
        for (int j = 0; j < 8; j++) tmp[j] = (_Float16)W1[(k0 + j) * C1 + n];
        *reinterpret_cast<half8*>(&w1sw[(size_t)slot * 8]) = tmp;
    } else if (b < PREPW_BLOCKS + W2PW_BLOCKS) {
        const int slot = (b - PREPW_BLOCKS) * 256 + tid;   // 0..1535
        const int lane = slot & 63;
        const int f = slot >> 6;          // 0..23
        const int nt = f % 3, ks = f / 3;
        const int n = nt * 16 + (lane & 15);
        const int k0 = ks * 32 + (lane >> 4) * 8;
        half8 tmp;
#pragma unroll
        for (int j = 0; j < 8; j++)
            tmp[j] = (n < NC) ? (_Float16)W2[(k0 + j) * NC + n] : (_Float16)0.f;
        *reinterpret_cast<half8*>(&w2sw[(size_t)slot * 8]) = tmp;
    } else {
        __shared__ int hcnt[NB];
        const int hb = b - PREPW_BLOCKS - W2PW_BLOCKS;
        if (tid < NB) hcnt[tid] = 0;
        __syncthreads();
        const int ET = E + N;
        const int per = (ET + HBLOCKS - 1) / HBLOCKS;
        const int lo = hb * per;
        const int hi = (lo + per < ET) ? (lo + per) : ET;
        const int st = edge_stride(ei);
        for (int i = lo + tid; i < hi; i += 256) {
            const int d = (i < E) ? ei[(size_t)st * (E + i)] : (i - E);
            atomicAdd(&hcnt[d >> BSHIFT], 1);
        }
        __syncthreads();
        if (tid < NB) hist[tid * HBLOCKS + hb] = hcnt[tid];
    }
}

// ---- K1: FUSED independent stages (both depend only on k_misc):
//      blocks [0, HBLOCKS)        : scatter with redundant 2D scan of hist
//      blocks [HBLOCKS, +G1_BLOCKS): h1 = x @ W1 via MFMA -> 4 quarter planes
//      Concurrent execution -> max instead of sum, one fewer launch gap.
__global__ __launch_bounds__(256) void k_fused1(
    const float* __restrict__ x, const _Float16* __restrict__ w1sw,
    const float* __restrict__ a1s, const float* __restrict__ a1d,
    __half* __restrict__ qh1, float* __restrict__ as1, float* __restrict__ ad1,
    const int* __restrict__ ei, int E, const int* __restrict__ hist,
    int* __restrict__ buck, int* __restrict__ bstart)
{
    const int tid = threadIdx.x;
    if (blockIdx.x < HBLOCKS) {
        // ---------------- scatter part ----------------
        __shared__ int cur[NB];
        __shared__ int bs[160];
        __shared__ int wbase[4];
        const int hb = blockIdx.x;
        const int lane = tid & 63, wid = tid >> 6;
        int rp = 0;
        if (tid < NB) {
            const int4* hp = (const int4*)&hist[tid * HBLOCKS];
            int s = 0;
#pragma unroll 4
            for (int k = 0; k < 64; k++) {
                const int4 v = hp[k];
                s += (v.x + v.y) + (v.z + v.w);
                const int b4 = 4 * k;
                rp += ((b4 + 0) < hb ? v.x : 0) + ((b4 + 1) < hb ? v.y : 0)
                    + ((b4 + 2) < hb ? v.z : 0) + ((b4 + 3) < hb ? v.w : 0);
            }
            bs[tid] = s;
        }
        __syncthreads();
        const int vin = (tid < NB) ? bs[tid] : 0;
        int v = vin;
#pragma unroll
        for (int off = 1; off < 64; off <<= 1) {
            const int u = __shfl_up(v, off, 64);
            if (lane >= off) v += u;
        }
        if (lane == 63) wbase[wid] = v;
        __syncthreads();
        if (tid < 64) {
            int w = (lane < 4) ? wbase[lane] : 0;
            const int orig = w;
#pragma unroll
            for (int off = 1; off < 4; off <<= 1) {
                const int u = __shfl_up(w, off, 64);
                if (lane >= off) w += u;
            }
            if (lane < 4) wbase[lane] = w - orig;
        }
        __syncthreads();
        if (tid < NB) {
            const int base = wbase[wid] + v - vin;
            cur[tid] = base + rp;
            if (hb == 0) bstart[tid] = base;
        }
        __syncthreads();
        const int ET = E + N;
        const int per = (ET + HBLOCKS - 1) / HBLOCKS;
        const int lo = hb * per;
        const int hi = (lo + per < ET) ? (lo + per) : ET;
        const int st = edge_stride(ei);
        for (int i = lo + tid; i < hi; i += 256) {
            int s, d;
            if (i < E) { s = ei[(size_t)st * i]; d = ei[(size_t)st * (E + i)]; }
            else       { s = i - E; d = i - E; }
            const int slot = atomicAdd(&cur[d >> BSHIFT], 1);
            buck[slot] = ((d & 127) << 16) | s;
        }
    } else {
        // ---------------- gemm1 part ----------------
        const int lane = tid & 63;
        const int wid = ((blockIdx.x - HBLOCKS) * 256 + tid) >> 6;   // 0..2503
        const int tile = wid >> 1;
        const int hs = wid & 1;                                      // col half
        const int m0 = tile * 16;
        const int g = lane >> 4, lm = lane & 15;
        const int arow = m0 + lm;
        half8 a[4];
        if (arow < N) {
            const float* xr = x + (size_t)arow * F;
#pragma unroll
            for (int ks = 0; ks < 4; ks++) {
                const float4 v0 = *reinterpret_cast<const float4*>(&xr[ks * 32 + g * 8]);
                const float4 v1 = *reinterpret_cast<const float4*>(&xr[ks * 32 + g * 8 + 4]);
                half8 t;
                t[0] = (_Float16)v0.x; t[1] = (_Float16)v0.y; t[2] = (_Float16)v0.z; t[3] = (_Float16)v0.w;
                t[4] = (_Float16)v1.x; t[5] = (_Float16)v1.y; t[6] = (_Float16)v1.z; t[7] = (_Float16)v1.w;
                a[ks] = t;
            }
        } else {
#pragma unroll
            for (int ks = 0; ks < 4; ks++) {
                half8 t;
#pragma unroll
                for (int j = 0; j < 8; j++) t[j] = (_Float16)0.f;
                a[ks] = t;
            }
        }
        const int rbase = m0 + g * 4;
        float ps[4] = {0.f, 0.f, 0.f, 0.f}, pd[4] = {0.f, 0.f, 0.f, 0.f};
#pragma unroll
        for (int ntl = 0; ntl < 8; ntl++) {
            const int nt = hs * 8 + ntl;
            f32x4 acc = {0.f, 0.f, 0.f, 0.f};
#pragma unroll
            for (int ks = 0; ks < 4; ks++) {
                const half8 bfr = *reinterpret_cast<const half8*>(&w1sw[(size_t)((ks * 16 + nt) * 64 + lane) * 8]);
                acc = __builtin_amdgcn_mfma_f32_16x16x32_f16(a[ks], bfr, acc, 0, 0, 0);
            }
            const int col = nt * 16 + lm;
            const int q = col >> 6, cq = col & 63;
            const float av = a1s[col], dv = a1d[col];
#pragma unroll
            for (int r = 0; r < 4; r++) {
                const int row = rbase + r;
                if (row < N) qh1[(size_t)q * QS + (size_t)row * 64 + cq] = __float2half((float)acc[r]);
                ps[r] = fmaf((float)acc[r], av, ps[r]);
                pd[r] = fmaf((float)acc[r], dv, pd[r]);
            }
            if (ntl & 1) {
#pragma unroll
                for (int off = 1; off <= 8; off <<= 1) {
#pragma unroll
                    for (int r = 0; r < 4; r++) {
                        ps[r] += __shfl_xor(ps[r], off);
                        pd[r] += __shfl_xor(pd[r], off);
                    }
                }
                if (lm == 0) {
                    const int head = hs * 4 + (ntl >> 1);
#pragma unroll
                    for (int r = 0; r < 4; r++) {
                        const int row = rbase + r;
                        if (row < N) {
                            as1[row * HEADS + head] = ps[r];
                            ad1[row * HEADS + head] = pd[r];
                        }
                    }
                }
#pragma unroll
                for (int r = 0; r < 4; r++) { ps[r] = 0.f; pd[r] = 0.f; }
            }
        }
    }
}

// ---- K4: per-bucket counting sort -> csr + rowptr (+ 64 zero sentinels past ET).
__global__ __launch_bounds__(256) void k_bucket(
    const int* __restrict__ bstart, const int* __restrict__ buck, int ET,
    int* __restrict__ csr, int* __restrict__ rowptr)
{
    __shared__ int cnt[128];
    __shared__ int pfx[128];
    const int b = blockIdx.x;
    const int tid = threadIdx.x;
    const int start = bstart[b];
    const int end = (b == NB - 1) ? ET : bstart[b + 1];
    if (tid < 128) cnt[tid] = 0;
    __syncthreads();
    for (int i = start + tid; i < end; i += 256)
        atomicAdd(&cnt[buck[i] >> 16], 1);
    __syncthreads();
    if (tid < 128) pfx[tid] = cnt[tid];
    __syncthreads();
    for (int off = 1; off < 128; off <<= 1) {
        int u = 0;
        if (tid < 128 && tid >= off) u = pfx[tid - off];
        __syncthreads();
        if (tid < 128) pfx[tid] += u;
        __syncthreads();
    }
    if (tid < 128) {
        const int node = b * 128 + tid;
        const int ebase = start + pfx[tid] - cnt[tid];
        if (node < N) rowptr[node] = ebase;
        cnt[tid] = ebase;
    }
    if (b == NB - 1 && tid == 0) rowptr[N] = ET;
    if (b == NB - 1 && tid < 64) csr[ET + tid] = 0;   // sentinels: safe 64-wide producer reads
    __syncthreads();
    for (int i = start + tid; i < end; i += 256) {
        const int val = buck[i];
        const int slot = atomicAdd(&cnt[val >> 16], 1);
        csr[slot] = val & 0xFFFF;
    }
}

// ---- K6: layer-1 aggregation on L2-resident quarter planes (R9 structure:
//      N/2 blocks, 8 node-slots, no grid-stride/prefetch — measured fastest).
//      Phase A stages {row byte-offset s<<7, w_head0, w_head1} into LDS
//      (one edge/lane, 2 exps). Phase B: LDS int4/float4 broadcast + 8
//      independent gathers; gather addr = base + 32-bit offset + lane*4
//      (kills the 64-bit per-gather address chain).
__global__ __launch_bounds__(256) void k_agg1(
    const int* __restrict__ rowptr, const int* __restrict__ csr,
    const __half* __restrict__ qh1,
    const float* __restrict__ as1, const float* __restrict__ ad1,
    const float* __restrict__ b1, __half* __restrict__ h1p)
{
    __shared__ __align__(16) float wlds[8][2][36];
    __shared__ __align__(16) int slds[8][36];
    const int tid = threadIdx.x;
    const int l5 = tid & 31;                     // lane within node group
    const int sub = tid >> 5;                    // node slot 0..7
    const int hq = blockIdx.x & 3;               // quarter -> XCD steering
    const int n = (blockIdx.x >> 2) * 8 + sub;   // node
    const int cq = l5 * 2;                       // channel pair within quarter
    const int lob = l5 * 4;                      // lane byte offset within 128B row
    const int hsel = l5 >> 4;                    // consumer head-sub (0/1)
    const float2 dv2 = *reinterpret_cast<const float2*>(&ad1[n * HEADS + hq * 2]);
    const int beg = rowptr[n], end = rowptr[n + 1];
    const char* planeb = (const char*)(qh1 + (size_t)hq * QS);
    float* w0 = wlds[sub][0];
    float* w1 = wlds[sub][1];
    const float* wc = wlds[sub][hsel];
    int* sl = slds[sub];
    float ax = 0.f, ay = 0.f, accw = 0.f;
    for (int cs = beg; cs < end; cs += 32) {
        const int m = end - cs;
        // phase A: one edge per lane -> LDS {s<<7, w0, w1}; zero-pad past m
        {
            const int s = csr[cs + l5];          // sentinel-safe
            const float2 a2 = *reinterpret_cast<const float2*>(&as1[s * HEADS + hq * 2]);
            const bool ok = l5 < m;
            sl[l5] = s << 7;
            w0[l5] = ok ? __expf(lrelu(a2.x + dv2.x)) : 0.f;
            w1[l5] = ok ? __expf(lrelu(a2.y + dv2.y)) : 0.f;
        }
        // phase B: 8 edges in flight (LDS int4/float4 broadcast + 8 gathers)
        const int mm8 = (m < 32) ? ((m + 7) & ~7) : 32;
        for (int j0 = 0; j0 < mm8; j0 += 8) {
            const int4 sa = *reinterpret_cast<const int4*>(&sl[j0]);
            const int4 sb = *reinterpret_cast<const int4*>(&sl[j0 + 4]);
            const float4 wa = *reinterpret_cast<const float4*>(&wc[j0]);
            const float4 wb = *reinterpret_cast<const float4*>(&wc[j0 + 4]);
            const float2 gA = __half22float2(*(const __half2*)(planeb + (unsigned)(sa.x + lob)));
            const float2 gB = __half22float2(*(const __half2*)(planeb + (unsigned)(sa.y + lob)));
            const float2 gC = __half22float2(*(const __half2*)(planeb + (unsigned)(sa.z + lob)));
            const float2 gD = __half22float2(*(const __half2*)(planeb + (unsigned)(sa.w + lob)));
            const float2 gE = __half22float2(*(const __half2*)(planeb + (unsigned)(sb.x + lob)));
            const float2 gF = __half22float2(*(const __half2*)(planeb + (unsigned)(sb.y + lob)));
            const float2 gG = __half22float2(*(const __half2*)(planeb + (unsigned)(sb.z + lob)));
            const float2 gH = __half22float2(*(const __half2*)(planeb + (unsigned)(sb.w + lob)));
            accw += (wa.x + wa.y) + (wa.z + wa.w) + (wb.x + wb.y) + (wb.z + wb.w);
            ax = fmaf(wa.x, gA.x, ax); ay = fmaf(wa.x, gA.y, ay);
            ax = fmaf(wa.y, gB.x, ax); ay = fmaf(wa.y, gB.y, ay);
            ax = fmaf(wa.z, gC.x, ax); ay = fmaf(wa.z, gC.y, ay);
            ax = fmaf(wa.w, gD.x, ax); ay = fmaf(wa.w, gD.y, ay);
            ax = fmaf(wb.x, gE.x, ax); ay = fmaf(wb.x, gE.y, ay);
            ax = fmaf(wb.y, gF.x, ax); ay = fmaf(wb.y, gF.y, ay);
            ax = fmaf(wb.z, gG.x, ax); ay = fmaf(wb.z, gG.y, ay);
            ax = fmaf(wb.w, gH.x, ax); ay = fmaf(wb.w, gH.y, ay);
        }
    }
    const float inv = 1.f / accw;
    const int ch = hq * 64 + cq;
    float ox = ax * inv + b1[ch];
    float oy = ay * inv + b1[ch + 1];
    ox = (ox > 0.f) ? ox : (__expf(ox) - 1.f);
    oy = (oy > 0.f) ? oy : (__expf(oy) - 1.f);
    *reinterpret_cast<__half2*>(&h1p[(size_t)n * C1 + ch]) = __floats2half2_rn(ox, oy);
}

// ---- K7: h2 = h1p @ W2 via MFMA (NC=40 padded to 3x16 col tiles); fused as2/ad2.
//      h2h stored with row stride NCP=64 halves (128B = exactly one cache line).
__global__ __launch_bounds__(256) void k_gemm2_mfma(
    const __half* __restrict__ h1p, const _Float16* __restrict__ w2sw,
    const float* __restrict__ a2s, const float* __restrict__ a2d,
    __half* __restrict__ h2h, float* __restrict__ as2, float* __restrict__ ad2)
{
    const int lane = threadIdx.x & 63;
    const int wid = (blockIdx.x * 256 + threadIdx.x) >> 6;
    const int m0 = wid * 16;
    const int g = lane >> 4, lm = lane & 15;
    const int arow = m0 + lm;
    half8 a[8];
    if (arow < N) {
        const __half* hr = h1p + (size_t)arow * C1;
#pragma unroll
        for (int ks = 0; ks < 8; ks++)
            a[ks] = *reinterpret_cast<const half8*>(&hr[ks * 32 + g * 8]);
    } else {
#pragma unroll
        for (int ks = 0; ks < 8; ks++) {
            half8 t;
#pragma unroll
            for (int j = 0; j < 8; j++) t[j] = (_Float16)0.f;
            a[ks] = t;
        }
    }
    f32x4 acc[3];
#pragma unroll
    for (int nt = 0; nt < 3; nt++) acc[nt] = (f32x4){0.f, 0.f, 0.f, 0.f};
#pragma unroll
    for (int ks = 0; ks < 8; ks++) {
#pragma unroll
        for (int nt = 0; nt < 3; nt++) {
            const half8 bfr = *reinterpret_cast<const half8*>(&w2sw[(size_t)((ks * 3 + nt) * 64 + lane) * 8]);
            acc[nt] = __builtin_amdgcn_mfma_f32_16x16x32_f16(a[ks], bfr, acc[nt], 0, 0, 0);
        }
    }
    const int rbase = m0 + g * 4;
    float av[3], dvv[3];
#pragma unroll
    for (int nt = 0; nt < 3; nt++) {
        const int col = nt * 16 + lm;
        av[nt]  = (col < NC) ? a2s[col] : 0.f;
        dvv[nt] = (col < NC) ? a2d[col] : 0.f;
    }
#pragma unroll
    for (int r = 0; r < 4; r++) {
        const int row = rbase + r;
        float ps = 0.f, pd = 0.f;
#pragma unroll
        for (int nt = 0; nt < 3; nt++) {
            const float v = (float)acc[nt][r];
            const int col = nt * 16 + lm;
            if (row < N && col < NC) h2h[(size_t)row * NCP + col] = __float2half(v);
            ps = fmaf(v, av[nt], ps);
            pd = fmaf(v, dvv[nt], pd);
        }
#pragma unroll
        for (int off = 1; off <= 8; off <<= 1) {
            ps += __shfl_xor(ps, off);
            pd += __shfl_xor(pd, off);
        }
        if (lm == 0 && row < N) { as2[row] = ps; ad2[row] = pd; }
    }
}

// ---- K8: layer-2 aggregation + bias + log_softmax. One wave/node.
//      LDS stages {s<<7, w} per 64-edge burst (one exp/lane, inputs prefetched);
//      phase B 8 edges in flight, gather = base + 32-bit offset + cc*2.
__global__ __launch_bounds__(256) void k_agg2(
    const int* __restrict__ rowptr, const int* __restrict__ csr,
    const __half* __restrict__ h2h, const float* __restrict__ as2,
    const float* __restrict__ ad2, const float* __restrict__ b2,
    float* __restrict__ out)
{
    __shared__ __align__(16) float wl[4][68];
    __shared__ __align__(16) int sl2[4][68];
    const int lane = threadIdx.x & 63;
    const int wv = threadIdx.x >> 6;
    const int n = (blockIdx.x * blockDim.x + threadIdx.x) >> 6;
    const int c = lane;
    const int cc = (c < NC) ? c : (NC - 1);
    const int lob = cc * 2;                      // lane byte offset within 128B row
    const float adv = ad2[n];
    const int beg = rowptr[n], end = rowptr[n + 1];
    const char* h2b = (const char*)h2h;
    float* w = wl[wv];
    int* sl = sl2[wv];
    float acc = 0.f, accw = 0.f;
    // prefetch first burst's producer inputs (sentinel-safe)
    int s_pf = csr[beg + lane];
    float a_pf = as2[s_pf];
    for (int cs = beg; cs < end; cs += 64) {
        const int m = end - cs;
        // phase A: staged {s<<7, w} from prefetched inputs
        {
            sl[lane] = s_pf << 7;
            w[lane] = (lane < m) ? __expf(lrelu(a_pf + adv)) : 0.f;
        }
        if (cs + 64 < end) {
            s_pf = csr[cs + 64 + lane];        // sentinel-safe
            a_pf = as2[s_pf];
        }
        // phase B: 8 edges in flight
        const int mm8 = (m < 64) ? ((m + 7) & ~7) : 64;
        for (int j0 = 0; j0 < mm8; j0 += 8) {
            const int4 sa = *reinterpret_cast<const int4*>(&sl[j0]);
            const int4 sb = *reinterpret_cast<const int4*>(&sl[j0 + 4]);
            const float4 wa = *reinterpret_cast<const float4*>(&w[j0]);
            const float4 wb = *reinterpret_cast<const float4*>(&w[j0 + 4]);
            const float g0 = __half2float(*(const __half*)(h2b + (unsigned)(sa.x + lob)));
            const float g1 = __half2float(*(const __half*)(h2b + (unsigned)(sa.y + lob)));
            const float g2 = __half2float(*(const __half*)(h2b + (unsigned)(sa.z + lob)));
            const float g3 = __half2float(*(const __half*)(h2b + (unsigned)(sa.w + lob)));
            const float g4 = __half2float(*(const __half*)(h2b + (unsigned)(sb.x + lob)));
            const float g5 = __half2float(*(const __half*)(h2b + (unsigned)(sb.y + lob)));
            const float g6 = __half2float(*(const __half*)(h2b + (unsigned)(sb.z + lob)));
            const float g7 = __half2float(*(const __half*)(h2b + (unsigned)(sb.w + lob)));
            accw += (wa.x + wa.y) + (wa.z + wa.w) + (wb.x + wb.y) + (wb.z + wb.w);
            acc = fmaf(wa.x, g0, acc);
            acc = fmaf(wa.y, g1, acc);
            acc = fmaf(wa.z, g2, acc);
            acc = fmaf(wa.w, g3, acc);
            acc = fmaf(wb.x, g4, acc);
            acc = fmaf(wb.y, g5, acc);
            acc = fmaf(wb.z, g6, acc);
            acc = fmaf(wb.w, g7, acc);
        }
    }
    const float v = acc / accw + b2[cc];
    float m = (c < NC) ? v : -1e30f;
#pragma unroll
    for (int off = 32; off >= 1; off >>= 1) m = fmaxf(m, __shfl_xor(m, off));
    float S = (c < NC) ? __expf(v - m) : 0.f;
#pragma unroll
    for (int off = 32; off >= 1; off >>= 1) S += __shfl_xor(S, off);
    if (c < NC) out[(size_t)n * NC + c] = v - m - logf(S);
}

extern "C" void kernel_launch(void* const* d_in, const int* in_sizes, int n_in,
                              void* d_out, int out_size, void* d_ws, size_t ws_size,
                              hipStream_t stream)
{
    const float* x   = (const float*)d_in[0];
    const int*   ei  = (const int*)d_in[1];
    const float* W1  = (const float*)d_in[2];
    const float* a1s = (const float*)d_in[3];
    const float* a1d = (const float*)d_in[4];
    const float* b1  = (const float*)d_in[5];
    const float* W2  = (const float*)d_in[6];
    const float* a2s = (const float*)d_in[7];
    const float* a2d = (const float*)d_in[8];
    const float* b2  = (const float*)d_in[9];
    float* out = (float*)d_out;

    const int E  = in_sizes[1] / 2;
    const int ET = E + N;

    auto align64 = [](size_t v) { return (v + 63) & ~(size_t)63; };
    char* ws = (char*)d_ws;
    size_t off = 0;
    _Float16* w1sw = (_Float16*)(ws + off); off = align64(off + (size_t)4096 * 8 * 2);
    _Float16* w2sw = (_Float16*)(ws + off); off = align64(off + (size_t)1536 * 8 * 2);
    __half* qh1 = (__half*)(ws + off); off = align64(off + (size_t)N * C1 * 2);   // 4 quarter planes
    __half* h1p = (__half*)(ws + off); off = align64(off + (size_t)N * C1 * 2);
    __half* h2h = (__half*)(ws + off); off = align64(off + (size_t)N * NCP * 2);
    float* as1 = (float*)(ws + off); off = align64(off + (size_t)N * HEADS * 4);
    float* ad1 = (float*)(ws + off); off = align64(off + (size_t)N * HEADS * 4);
    float* as2 = (float*)(ws + off); off = align64(off + (size_t)N * 4);
    float* ad2 = (float*)(ws + off); off = align64(off + (size_t)N * 4);
    int* hist   = (int*)(ws + off); off = align64(off + (size_t)HM * 4);
    int* bstart = (int*)(ws + off); off = align64(off + (size_t)NB * 4);
    int* buck   = (int*)(ws + off); off = align64(off + (size_t)ET * 4);
    int* rowptr = (int*)(ws + off); off = align64(off + (size_t)(N + 1) * 4);
    int* csr    = (int*)(ws + off); off = align64(off + (size_t)ET * 4 + 256);

    k_misc<<<PREPW_BLOCKS + W2PW_BLOCKS + HBLOCKS, 256, 0, stream>>>(W1, w1sw, W2, w2sw, ei, E, hist);
    k_fused1<<<HBLOCKS + G1_BLOCKS, 256, 0, stream>>>(x, w1sw, a1s, a1d, qh1, as1, ad1,
                                                      ei, E, hist, buck, bstart);
    k_bucket<<<NB, 256, 0, stream>>>(bstart, buck, ET, csr, rowptr);
    k_agg1<<<N / 2, 256, 0, stream>>>(rowptr, csr, qh1, as1, ad1, b1, h1p);
    k_gemm2_mfma<<<313, 256, 0, stream>>>(h1p, w2sw, a2s, a2d, h2h, as2, ad2);
    k_agg2<<<5000, 256, 0, stream>>>(rowptr, csr, h2h, as2, ad2, b2, out);
}